// Round 4
// baseline (255.442 us; speedup 1.0000x reference)
//
#include <hip/hip_runtime.h>
#include <hip/hip_bf16.h>
#include <stdint.h>

// ---------------------------------------------------------------------------
// SSD (Mamba-2 chunked scan) B=2, L=4096, DM=1024, NH=32, HD=32, DS=64, CS=256
// R4: GEMMs: chunk-major LDS (kills 8-way bank conflicts), M-fast grid (XCD
// L2 A-reuse), in-proj epilogue routes x->bf16 xbf, B/C->bf16, dt->fp32 dtz
// (no fp32 xbcdt materialization, bc_cvt kernel removed).
// ---------------------------------------------------------------------------

typedef __bf16 bf16x8 __attribute__((ext_vector_type(8)));
typedef __bf16 bf16x4 __attribute__((ext_vector_type(4)));
typedef float  f32x4  __attribute__((ext_vector_type(4)));

#define MFMA16(a, b, c) __builtin_amdgcn_mfma_f32_16x16x32_bf16((a), (b), (c), 0, 0, 0)

__device__ __forceinline__ void async_copy16(const __bf16* g, __bf16* l) {
    __builtin_amdgcn_global_load_lds((const __attribute__((address_space(1))) void*)g,
                                     (__attribute__((address_space(3))) void*)l,
                                     16, 0, 0);
}

// ---------------------------------------------------------------------------
__global__ void cvt_f32_bf16(const float* __restrict__ in, __bf16* __restrict__ out, int n) {
    int i = (blockIdx.x * 256 + threadIdx.x) * 4;
    if (i + 3 < n) {
        float4 v = *(const float4*)(in + i);
        bf16x4 o;
        o[0] = (__bf16)v.x; o[1] = (__bf16)v.y; o[2] = (__bf16)v.z; o[3] = (__bf16)v.w;
        *(bf16x4*)(out + i) = o;
    } else {
        for (int k = i; k < n; ++k) out[k] = (__bf16)in[k];
    }
}

// ---------------------------------------------------------------------------
// GEMM core: 128x128 tile, BK=32, chunk-major LDS (plane = k-chunk of 8),
// M-fast grid. mode 0: plain fp32 out (N=1024). mode 1: routed epilogue.
// ---------------------------------------------------------------------------
__global__ __launch_bounds__(256) void gemm_fused(
    const __bf16* __restrict__ A, const __bf16* __restrict__ Bt,
    int K, int Nrows, int mode,
    float* __restrict__ Cout, __bf16* __restrict__ xbf,
    __bf16* __restrict__ Bbf, __bf16* __restrict__ Cbf,
    float* __restrict__ dtz)
{
    __shared__ __attribute__((aligned(16))) __bf16 As[4096];  // [plane][row][8]
    __shared__ __attribute__((aligned(16))) __bf16 Bs[4096];
    const int tid = threadIdx.x;
    const int m0 = blockIdx.x * 128;       // M-fast: same-A blocks share XCD
    const int n0 = blockIdx.y * 128;
    const int w = tid >> 6, lane = tid & 63;
    const int wm = w >> 1, wn = w & 1;
    const int fr = lane & 15, quad = lane >> 4;

    const int half = w & 1, pl = w >> 1;
    const int arow = m0 + half * 64 + lane;
    const int brow = min(n0 + half * 64 + lane, Nrows - 1);
    const __bf16* aP0 = A + (size_t)arow * K + pl * 8;
    const __bf16* aP1 = A + (size_t)arow * K + (pl + 2) * 8;
    const __bf16* bP0 = Bt + (size_t)brow * K + pl * 8;
    const __bf16* bP1 = Bt + (size_t)brow * K + (pl + 2) * 8;
    __bf16* dA0 = As + pl * 1024 + half * 512;
    __bf16* dA1 = As + (pl + 2) * 1024 + half * 512;
    __bf16* dB0 = Bs + pl * 1024 + half * 512;
    __bf16* dB1 = Bs + (pl + 2) * 1024 + half * 512;

    f32x4 acc[4][4] = {};

    for (int kt = 0; kt < K; kt += 32) {
        async_copy16(aP0 + kt, dA0);
        async_copy16(aP1 + kt, dA1);
        async_copy16(bP0 + kt, dB0);
        async_copy16(bP1 + kt, dB1);
        __syncthreads();
        bf16x8 af[4], bfv[4];
#pragma unroll
        for (int a = 0; a < 4; ++a)
            af[a] = *(const bf16x8*)&As[quad * 1024 + (wm * 64 + a * 16 + fr) * 8];
#pragma unroll
        for (int b = 0; b < 4; ++b)
            bfv[b] = *(const bf16x8*)&Bs[quad * 1024 + (wn * 64 + b * 16 + fr) * 8];
#pragma unroll
        for (int a = 0; a < 4; ++a)
#pragma unroll
            for (int b = 0; b < 4; ++b)
                acc[a][b] = MFMA16(af[a], bfv[b], acc[a][b]);
        __syncthreads();
    }

    const int rowb = quad * 4;
    if (mode == 0) {
        // plain fp32, Nvalid = 1024
#pragma unroll
        for (int a = 0; a < 4; ++a)
#pragma unroll
            for (int b = 0; b < 4; ++b) {
                int col = n0 + wn * 64 + b * 16 + fr;
#pragma unroll
                for (int q = 0; q < 4; ++q) {
                    int row = m0 + wm * 64 + a * 16 + rowb + q;
                    Cout[(size_t)row * 1024 + col] = acc[a][b][q];
                }
            }
    } else if (blockIdx.y < 8) {
        // x part -> bf16 xbf[row][1024]
#pragma unroll
        for (int a = 0; a < 4; ++a)
#pragma unroll
            for (int b = 0; b < 4; ++b) {
                int col = n0 + wn * 64 + b * 16 + fr;
#pragma unroll
                for (int q = 0; q < 4; ++q) {
                    int row = m0 + wm * 64 + a * 16 + rowb + q;
                    xbf[(size_t)row * 1024 + col] = (__bf16)acc[a][b][q];
                }
            }
    } else if (blockIdx.y == 8) {
        // B (cl<64) / C (cl>=64) -> bf16 [row][64]
#pragma unroll
        for (int a = 0; a < 4; ++a)
#pragma unroll
            for (int b = 0; b < 4; ++b) {
                int cl = wn * 64 + b * 16 + fr;
#pragma unroll
                for (int q = 0; q < 4; ++q) {
                    int row = m0 + wm * 64 + a * 16 + rowb + q;
                    if (cl < 64) Bbf[(size_t)row * 64 + cl] = (__bf16)acc[a][b][q];
                    else         Cbf[(size_t)row * 64 + cl - 64] = (__bf16)acc[a][b][q];
                }
            }
    } else {
        // dt pre-activation -> fp32 dtz[row][32]
#pragma unroll
        for (int a = 0; a < 4; ++a)
#pragma unroll
            for (int b = 0; b < 4; ++b) {
                int cl = wn * 64 + b * 16 + fr;
                if (cl < 32) {
#pragma unroll
                    for (int q = 0; q < 4; ++q) {
                        int row = m0 + wm * 64 + a * 16 + rowb + q;
                        dtz[(size_t)row * 32 + cl] = acc[a][b][q];
                    }
                }
            }
    }
}

// ---------------------------------------------------------------------------
// prep: dt = softplus(dtz + dt_bias), a = dt*A, inclusive cumsum per (b,c,h)
// ---------------------------------------------------------------------------
__global__ __launch_bounds__(256) void prep_kernel(
    const float* __restrict__ dtz, const float* __restrict__ dt_bias,
    const float* __restrict__ A_log,
    float* __restrict__ dt_out, float* __restrict__ acum_out)
{
    const int h = blockIdx.x, c = blockIdx.y, b = blockIdx.z;
    const int i = threadIdx.x;
    const size_t row = (size_t)b * 4096 + c * 256 + i;
    float z = dtz[row * 32 + h] + dt_bias[h];
    float dtv = (z > 20.f) ? z : log1pf(expf(z));
    float Av = -expf(A_log[h]);
    float val = dtv * Av;
    __shared__ float buf[256];
    buf[i] = val;
    __syncthreads();
#pragma unroll
    for (int off = 1; off < 256; off <<= 1) {
        float add = (i >= off) ? buf[i - off] : 0.f;
        __syncthreads();
        val += add;
        buf[i] = val;
        __syncthreads();
    }
    const size_t bch = ((size_t)(b * 16 + c) * 32 + h) * 256;
    dt_out[bch + i]   = dtv;
    acum_out[bch + i] = val;
}

// ---------------------------------------------------------------------------
// xdtT: per (b,c,h) transpose of (x*dt) chunk -> xdtT[b,c,h,p,j] bf16
// ---------------------------------------------------------------------------
__global__ __launch_bounds__(256) void xdtt_kernel(
    const __bf16* __restrict__ xbf, const float* __restrict__ dtb,
    __bf16* __restrict__ xdtT)
{
    const int h = blockIdx.x, c = blockIdx.y, b = blockIdx.z;
    const size_t bc = (size_t)b * 16 + c;
    const size_t bch = bc * 32 + h;
    __shared__ __attribute__((aligned(16))) __bf16 tile[256][40];
    __shared__ float dts[256];
    const int t = threadIdx.x;
    dts[t] = dtb[bch * 256 + t];
    __syncthreads();
#pragma unroll
    for (int it = 0; it < 4; ++it) {
        int id = it * 256 + t;
        int j = id >> 2, pg = id & 3;
        bf16x8 v = *(const bf16x8*)&xbf[(bc * 256 + j) * 1024 + h * 32 + pg * 8];
        float d = dts[j];
        bf16x8 o;
#pragma unroll
        for (int e = 0; e < 8; ++e) o[e] = (__bf16)((float)v[e] * d);
        *(bf16x8*)&tile[j][pg * 8] = o;
    }
    __syncthreads();
#pragma unroll
    for (int it = 0; it < 4; ++it) {
        int id = it * 256 + t;
        int p = id >> 5, jg = id & 31;
        bf16x8 o;
#pragma unroll
        for (int e = 0; e < 8; ++e) o[e] = tile[jg * 8 + e][p];
        *(bf16x8*)&xdtT[bch * 8192 + p * 256 + jg * 8] = o;
    }
}

// ---------------------------------------------------------------------------
// states: per (b,c,h): states[p,n] = sum_j xdt[p,j] * B[j,n] * exp(alast-a_j)
// ---------------------------------------------------------------------------
__global__ __launch_bounds__(256) void states_kernel(
    const __bf16* __restrict__ Bbf, const float* __restrict__ acum,
    const __bf16* __restrict__ xdtT, float* __restrict__ states)
{
    const int h = blockIdx.x, c = blockIdx.y, b = blockIdx.z;
    const size_t bc = (size_t)b * 16 + c;
    const size_t bch = bc * 32 + h;
    __shared__ __attribute__((aligned(16))) __bf16 Bsh[256 * 64];
    __shared__ __attribute__((aligned(16))) __bf16 BdT[64][264];
    __shared__ float decs[256];
    __shared__ float alast_sh;
    const int t = threadIdx.x, wave = t >> 6, lane = t & 63;

    const __bf16* Bsrc = Bbf + bc * 16384;
#pragma unroll
    for (int cc = 0; cc < 8; ++cc) {
        int s = wave * 8 + cc;
        int row = s * 8 + (lane >> 3);
        async_copy16(Bsrc + row * 64 + (lane & 7) * 8, Bsh + s * 512);
    }
    float a = acum[bch * 256 + t];
    if (t == 255) alast_sh = a;
    __syncthreads();
    decs[t] = __expf(alast_sh - a);
    __syncthreads();
    for (int idx = t; idx < 256 * 64; idx += 256) {
        int j = idx >> 6, n = idx & 63;
        BdT[n][j] = (__bf16)((float)Bsh[j * 64 + n] * decs[j]);
    }
    __syncthreads();
    const int fr = lane & 15, fk = (lane >> 4) * 8;
    const int mt  = wave >> 1;
    const int ntb = (wave & 1) * 2;
    f32x4 acc[2] = {};
    const __bf16* xrow = xdtT + bch * 8192;
#pragma unroll
    for (int ks = 0; ks < 8; ++ks) {
        bf16x8 af = *(const bf16x8*)&xrow[(mt * 16 + fr) * 256 + ks * 32 + fk];
#pragma unroll
        for (int nb = 0; nb < 2; ++nb) {
            bf16x8 bfv = *(const bf16x8*)&BdT[(ntb + nb) * 16 + fr][ks * 32 + fk];
            acc[nb] = MFMA16(af, bfv, acc[nb]);
        }
    }
    const int rowb = (lane >> 4) * 4;
#pragma unroll
    for (int nb = 0; nb < 2; ++nb)
#pragma unroll
        for (int q = 0; q < 4; ++q) {
            int p = mt * 16 + rowb + q;
            int n = (ntb + nb) * 16 + fr;
            states[bch * 2048 + p * 64 + n] = acc[nb][q];
        }
}

// ---------------------------------------------------------------------------
// scan: prev[b,c] = prev[b,c-1]*exp(alast[c-1]) + states[c-1]; bf16 out.
// ---------------------------------------------------------------------------
__global__ void scan_kernel(const float* __restrict__ states,
                            const float* __restrict__ acum,
                            __bf16* __restrict__ prevbf)
{
    int t = blockIdx.x * 256 + threadIdx.x;
    int n = t & 63, p = (t >> 6) & 31, h = (t >> 11) & 31, b = t >> 16;
    float s = 0.f;
    for (int c = 0; c < 16; ++c) {
        size_t bch = ((size_t)(b * 16 + c) * 32 + h);
        size_t off = bch * 2048 + (size_t)p * 64 + n;
        prevbf[off] = (__bf16)s;
        float dec = __expf(acum[bch * 256 + 255]);
        s = s * dec + states[off];
    }
}

// ---------------------------------------------------------------------------
// y: block=(b,c,h); 4 waves; wave w owns row-subtiles {w, w+4, w+8, w+12}.
// ---------------------------------------------------------------------------
__global__ __launch_bounds__(256, 2) void y_kernel(
    const __bf16* __restrict__ Bbf, const __bf16* __restrict__ Cbf,
    const float* __restrict__ acum, const __bf16* __restrict__ xdtT,
    const __bf16* __restrict__ prevbf, const __bf16* __restrict__ xbf,
    const float* __restrict__ Dp, __bf16* __restrict__ ybf)
{
    const int bidx = blockIdx.x;
    const int bc = bidx & 31, h = bidx >> 5;
    const size_t bch = (size_t)bc * 32 + h;
    __shared__ __attribute__((aligned(16))) __bf16 Bsh[256 * 64];
    __shared__ __attribute__((aligned(16))) __bf16 xsh[32 * 256];
    __shared__ __attribute__((aligned(16))) __bf16 Gw[4][16 * 72];
    __shared__ float ash[256];
    const int t = threadIdx.x, w = t >> 6, lane = t & 63;
    const int fr = lane & 15, q = lane >> 4;

    const __bf16* Bsrc = Bbf + (size_t)bc * 16384;
#pragma unroll
    for (int cc = 0; cc < 8; ++cc) {
        int s = w * 8 + cc;
        int row = s * 8 + (lane >> 3);
        int ch = (lane & 7) ^ ((lane >> 3) & 7);
        async_copy16(Bsrc + row * 64 + ch * 8, Bsh + s * 512);
    }
    const __bf16* xsrc = xdtT + bch * 8192;
#pragma unroll
    for (int cc = 0; cc < 4; ++cc) {
        int s = w * 4 + cc;
        int p = s * 2 + (lane >> 5);
        int cl = lane & 31;
        int ch = (cl & 24) | ((cl & 7) ^ (p & 7));
        async_copy16(xsrc + p * 256 + ch * 8, xsh + s * 512);
    }
    ash[t] = acum[bch * 256 + t];
    __syncthreads();

    bf16x8 cf[4][2], pf[2][2];
    float ei4[4];
#pragma unroll
    for (int s4 = 0; s4 < 4; ++s4) {
        int i = (w + 4 * s4) * 16 + fr;
        const __bf16* cp = Cbf + ((size_t)bc * 256 + i) * 64 + q * 8;
        cf[s4][0] = *(const bf16x8*)cp;
        cf[s4][1] = *(const bf16x8*)(cp + 32);
        ei4[s4] = __expf(ash[i]);
    }
#pragma unroll
    for (int mt = 0; mt < 2; ++mt) {
        const __bf16* pp = prevbf + bch * 2048 + (size_t)(mt * 16 + fr) * 64 + q * 8;
        pf[mt][0] = *(const bf16x8*)pp;
        pf[mt][1] = *(const bf16x8*)(pp + 32);
    }
    float ai[4][4];
#pragma unroll
    for (int s4 = 0; s4 < 4; ++s4)
#pragma unroll
        for (int r = 0; r < 4; ++r)
            ai[s4][r] = ash[(w + 4 * s4) * 16 + q * 4 + r];

    f32x4 acc[4][2] = {};

#pragma unroll
    for (int jt = 0; jt < 4; ++jt) {
        bf16x8 bb[4][2], xa[2][2];
#pragma unroll
        for (int nt = 0; nt < 4; ++nt) {
            int j = jt * 64 + nt * 16 + fr;
#pragma unroll
            for (int ks = 0; ks < 2; ++ks) {
                int ch = (q + 4 * ks) ^ (fr & 7);
                bb[nt][ks] = *(const bf16x8*)&Bsh[j * 64 + ch * 8];
            }
        }
#pragma unroll
        for (int mt = 0; mt < 2; ++mt) {
            int p = mt * 16 + fr;
#pragma unroll
            for (int ks = 0; ks < 2; ++ks) {
                int ch = 8 * jt + ((q + 4 * ks) ^ (p & 7));
                xa[mt][ks] = *(const bf16x8*)&xsh[p * 256 + ch * 8];
            }
        }
#pragma unroll
        for (int s4 = 0; s4 < 4; ++s4) {
            int si = w + 4 * s4;
            if (si < 4 * jt) continue;
            f32x4 sreg[4];
#pragma unroll
            for (int nt = 0; nt < 4; ++nt) {
                f32x4 z = {};
                z = MFMA16(cf[s4][0], bb[nt][0], z);
                z = MFMA16(cf[s4][1], bb[nt][1], z);
                sreg[nt] = z;
            }
#pragma unroll
            for (int nt = 0; nt < 4; ++nt) {
                int j = jt * 64 + nt * 16 + fr;
                float aj = ash[j];
#pragma unroll
                for (int r = 0; r < 4; ++r) {
                    int i = si * 16 + q * 4 + r;
                    float v = (j <= i) ? sreg[nt][r] * __expf(ai[s4][r] - aj) : 0.f;
                    Gw[w][(q * 4 + r) * 72 + nt * 16 + fr] = (__bf16)v;
                }
            }
            bf16x8 g0 = *(const bf16x8*)&Gw[w][fr * 72 + q * 8];
            bf16x8 g1 = *(const bf16x8*)&Gw[w][fr * 72 + 32 + q * 8];
#pragma unroll
            for (int mt = 0; mt < 2; ++mt) {
                acc[s4][mt] = MFMA16(xa[mt][0], g0, acc[s4][mt]);
                acc[s4][mt] = MFMA16(xa[mt][1], g1, acc[s4][mt]);
            }
        }
    }

#pragma unroll
    for (int s4 = 0; s4 < 4; ++s4) {
#pragma unroll
        for (int ks = 0; ks < 2; ++ks) {
            bf16x8 ce;
#pragma unroll
            for (int e = 0; e < 8; ++e)
                ce[e] = (__bf16)((float)cf[s4][ks][e] * ei4[s4]);
#pragma unroll
            for (int mt = 0; mt < 2; ++mt)
                acc[s4][mt] = MFMA16(pf[mt][ks], ce, acc[s4][mt]);
        }
    }

    const float Dv = Dp[h];
#pragma unroll
    for (int s4 = 0; s4 < 4; ++s4) {
        int i = (w + 4 * s4) * 16 + fr;
        size_t row = (size_t)bc * 256 + i;
#pragma unroll
        for (int mt = 0; mt < 2; ++mt) {
            int p0 = mt * 16 + q * 4;
            bf16x4 xv = *(const bf16x4*)&xbf[row * 1024 + h * 32 + p0];
            bf16x4 o;
#pragma unroll
            for (int e = 0; e < 4; ++e)
                o[e] = (__bf16)(acc[s4][mt][e] + (float)xv[e] * Dv);
            *(bf16x4*)&ybf[row * 1024 + h * 32 + p0] = o;
        }
    }
}

// ---------------------------------------------------------------------------
extern "C" void kernel_launch(void* const* d_in, const int* in_sizes, int n_in,
                              void* d_out, int out_size, void* d_ws, size_t ws_size,
                              hipStream_t stream)
{
    (void)in_sizes; (void)n_in; (void)out_size;
    const float* u       = (const float*)d_in[0];
    const float* W_in    = (const float*)d_in[1];
    const float* dt_bias = (const float*)d_in[2];
    const float* A_log   = (const float*)d_in[3];
    const float* Dp      = (const float*)d_in[4];
    const float* W_out   = (const float*)d_in[5];
    float* out = (float*)d_out;

    if (ws_size < 72679424) return;

    char* ws = (char*)d_ws;
    __bf16* u_bf    = (__bf16*)(ws);                  // 16,777,216 (reused as ybf)
    __bf16* win_bf  = (__bf16*)(ws + 16777216);       //  2,424,832
    __bf16* wout_bf = (__bf16*)(ws + 19202048);       //  2,097,152
    __bf16* xbf     = (__bf16*)(ws + 21299200);       // 16,777,216
    float*  dtz     = (float*) (ws + 38076416);       //  1,048,576
    float*  dtb     = (float*) (ws + 39124992);       //  1,048,576
    float*  acum    = (float*) (ws + 40173568);       //  1,048,576
    __bf16* xdtT    = (__bf16*)(ws + 41222144);       // 16,777,216
    float*  states  = (float*) (ws + 57999360);       //  8,388,608
    __bf16* prevbf  = (__bf16*)(ws + 66387968);       //  4,194,304
    __bf16* Bbf     = (__bf16*)(ws + 70582272);       //  1,048,576
    __bf16* Cbf     = (__bf16*)(ws + 71630848);       //  1,048,576

    cvt_f32_bf16<<<8192, 256, 0, stream>>>(u, u_bf, 8388608);
    cvt_f32_bf16<<<1184, 256, 0, stream>>>(W_in, win_bf, 1212416);
    cvt_f32_bf16<<<1024, 256, 0, stream>>>(W_out, wout_bf, 1048576);

    gemm_fused<<<dim3(64, 10), 256, 0, stream>>>(u_bf, win_bf, 1024, 1184, 1,
                                                 nullptr, xbf, Bbf, Cbf, dtz);

    prep_kernel<<<dim3(32, 16, 2), 256, 0, stream>>>(dtz, dt_bias, A_log, dtb, acum);
    xdtt_kernel<<<dim3(32, 16, 2), 256, 0, stream>>>(xbf, dtb, xdtT);
    states_kernel<<<dim3(32, 16, 2), 256, 0, stream>>>(Bbf, acum, xdtT, states);
    scan_kernel<<<512, 256, 0, stream>>>(states, acum, prevbf);

    __bf16* ybf = u_bf;  // u_bf dead after gemm1
    y_kernel<<<1024, 256, 0, stream>>>(Bbf, Cbf, acum, xdtT, prevbf,
                                       xbf, Dp, ybf);

    gemm_fused<<<dim3(64, 8), 256, 0, stream>>>(ybf, wout_bf, 1024, 1024, 0,
                                                out, nullptr, nullptr, nullptr, nullptr);
}

// Round 5
// 231.290 us; speedup vs baseline: 1.1044x; 1.1044x over previous
//
#include <hip/hip_runtime.h>
#include <hip/hip_bf16.h>
#include <stdint.h>

// ---------------------------------------------------------------------------
// SSD (Mamba-2 chunked scan) B=2, L=4096, DM=1024, NH=32, HD=32, DS=64, CS=256
// R5: gemm staging = coalesced global (4 lanes/row, chunk-permuted within the
// row's 64B segment) + XOR-swizzled LDS layout -> conflict-free fragment reads.
// Fixes R4's uncoalesced stride-K staging while keeping R4's zero conflicts.
// ---------------------------------------------------------------------------

typedef __bf16 bf16x8 __attribute__((ext_vector_type(8)));
typedef __bf16 bf16x4 __attribute__((ext_vector_type(4)));
typedef float  f32x4  __attribute__((ext_vector_type(4)));

#define MFMA16(a, b, c) __builtin_amdgcn_mfma_f32_16x16x32_bf16((a), (b), (c), 0, 0, 0)

__device__ __forceinline__ void async_copy16(const __bf16* g, __bf16* l) {
    __builtin_amdgcn_global_load_lds((const __attribute__((address_space(1))) void*)g,
                                     (__attribute__((address_space(3))) void*)l,
                                     16, 0, 0);
}

// ---------------------------------------------------------------------------
__global__ void cvt_f32_bf16(const float* __restrict__ in, __bf16* __restrict__ out, int n) {
    int i = (blockIdx.x * 256 + threadIdx.x) * 4;
    if (i + 3 < n) {
        float4 v = *(const float4*)(in + i);
        bf16x4 o;
        o[0] = (__bf16)v.x; o[1] = (__bf16)v.y; o[2] = (__bf16)v.z; o[3] = (__bf16)v.w;
        *(bf16x4*)(out + i) = o;
    } else {
        for (int k = i; k < n; ++k) out[k] = (__bf16)in[k];
    }
}

// ---------------------------------------------------------------------------
// GEMM core: 128x128 tile, BK=32.
// LDS layout: element offset = row*32 + p*8, where position p holds global
// k-chunk c = p ^ ((row>>1)&3).
// Staging (per instruction, 16 rows): lane l -> row r0+(l>>2),
// chunk (l&3)^((l>>3)&3)  => coalesced 64B/row segments, LDS slots = lane.
// Fragment read: pos = quad ^ ((fr>>1)&3) => all 8 bank-groups per 16-lane
// batch, 2 lanes each (free).
// ---------------------------------------------------------------------------
__global__ __launch_bounds__(256) void gemm_fused(
    const __bf16* __restrict__ A, const __bf16* __restrict__ Bt,
    int K, int Nrows, int mode,
    float* __restrict__ Cout, __bf16* __restrict__ xbf,
    __bf16* __restrict__ Bbf, __bf16* __restrict__ Cbf,
    float* __restrict__ dtz)
{
    __shared__ __attribute__((aligned(16))) __bf16 As[4096];
    __shared__ __attribute__((aligned(16))) __bf16 Bs[4096];
    const int tid = threadIdx.x;
    const int m0 = blockIdx.x * 128;       // M-fast: same-A blocks share XCD
    const int n0 = blockIdx.y * 128;
    const int w = tid >> 6, lane = tid & 63;
    const int wm = w >> 1, wn = w & 1;
    const int fr = lane & 15, quad = lane >> 4;
    const int sw = quad ^ ((fr >> 1) & 3);         // fragment-read position

    // staging addresses: wave w owns rows [w*32, w*32+32) of both tiles
    const int lr  = lane >> 2;                      // row within 16-row group
    const int lc8 = (((lane & 3) ^ ((lane >> 3) & 3))) * 8;  // swizzled chunk
    const int ra0 = m0 + w * 32 + lr;
    const int ra1 = ra0 + 16;
    const int rb0 = min(n0 + w * 32 + lr, Nrows - 1);
    const int rb1 = min(n0 + w * 32 + 16 + lr, Nrows - 1);
    const __bf16* aP0 = A + (size_t)ra0 * K + lc8;
    const __bf16* aP1 = A + (size_t)ra1 * K + lc8;
    const __bf16* bP0 = Bt + (size_t)rb0 * K + lc8;
    const __bf16* bP1 = Bt + (size_t)rb1 * K + lc8;
    __bf16* dA0 = As + w * 1024;
    __bf16* dA1 = As + w * 1024 + 512;
    __bf16* dB0 = Bs + w * 1024;
    __bf16* dB1 = Bs + w * 1024 + 512;

    f32x4 acc[4][4] = {};

    for (int kt = 0; kt < K; kt += 32) {
        async_copy16(aP0 + kt, dA0);
        async_copy16(aP1 + kt, dA1);
        async_copy16(bP0 + kt, dB0);
        async_copy16(bP1 + kt, dB1);
        __syncthreads();
        bf16x8 af[4], bfv[4];
#pragma unroll
        for (int a = 0; a < 4; ++a)
            af[a] = *(const bf16x8*)&As[(wm * 64 + a * 16 + fr) * 32 + sw * 8];
#pragma unroll
        for (int b = 0; b < 4; ++b)
            bfv[b] = *(const bf16x8*)&Bs[(wn * 64 + b * 16 + fr) * 32 + sw * 8];
#pragma unroll
        for (int a = 0; a < 4; ++a)
#pragma unroll
            for (int b = 0; b < 4; ++b)
                acc[a][b] = MFMA16(af[a], bfv[b], acc[a][b]);
        __syncthreads();
    }

    const int rowb = quad * 4;
    if (mode == 0) {
#pragma unroll
        for (int a = 0; a < 4; ++a)
#pragma unroll
            for (int b = 0; b < 4; ++b) {
                int col = n0 + wn * 64 + b * 16 + fr;
#pragma unroll
                for (int q = 0; q < 4; ++q) {
                    int row = m0 + wm * 64 + a * 16 + rowb + q;
                    Cout[(size_t)row * 1024 + col] = acc[a][b][q];
                }
            }
    } else if (blockIdx.y < 8) {
#pragma unroll
        for (int a = 0; a < 4; ++a)
#pragma unroll
            for (int b = 0; b < 4; ++b) {
                int col = n0 + wn * 64 + b * 16 + fr;
#pragma unroll
                for (int q = 0; q < 4; ++q) {
                    int row = m0 + wm * 64 + a * 16 + rowb + q;
                    xbf[(size_t)row * 1024 + col] = (__bf16)acc[a][b][q];
                }
            }
    } else if (blockIdx.y == 8) {
#pragma unroll
        for (int a = 0; a < 4; ++a)
#pragma unroll
            for (int b = 0; b < 4; ++b) {
                int cl = wn * 64 + b * 16 + fr;
#pragma unroll
                for (int q = 0; q < 4; ++q) {
                    int row = m0 + wm * 64 + a * 16 + rowb + q;
                    if (cl < 64) Bbf[(size_t)row * 64 + cl] = (__bf16)acc[a][b][q];
                    else         Cbf[(size_t)row * 64 + cl - 64] = (__bf16)acc[a][b][q];
                }
            }
    } else {
#pragma unroll
        for (int a = 0; a < 4; ++a)
#pragma unroll
            for (int b = 0; b < 4; ++b) {
                int cl = wn * 64 + b * 16 + fr;
                if (cl < 32) {
#pragma unroll
                    for (int q = 0; q < 4; ++q) {
                        int row = m0 + wm * 64 + a * 16 + rowb + q;
                        dtz[(size_t)row * 32 + cl] = acc[a][b][q];
                    }
                }
            }
    }
}

// ---------------------------------------------------------------------------
// prep: dt = softplus(dtz + dt_bias), a = dt*A, inclusive cumsum per (b,c,h)
// ---------------------------------------------------------------------------
__global__ __launch_bounds__(256) void prep_kernel(
    const float* __restrict__ dtz, const float* __restrict__ dt_bias,
    const float* __restrict__ A_log,
    float* __restrict__ dt_out, float* __restrict__ acum_out)
{
    const int h = blockIdx.x, c = blockIdx.y, b = blockIdx.z;
    const int i = threadIdx.x;
    const size_t row = (size_t)b * 4096 + c * 256 + i;
    float z = dtz[row * 32 + h] + dt_bias[h];
    float dtv = (z > 20.f) ? z : log1pf(expf(z));
    float Av = -expf(A_log[h]);
    float val = dtv * Av;
    __shared__ float buf[256];
    buf[i] = val;
    __syncthreads();
#pragma unroll
    for (int off = 1; off < 256; off <<= 1) {
        float add = (i >= off) ? buf[i - off] : 0.f;
        __syncthreads();
        val += add;
        buf[i] = val;
        __syncthreads();
    }
    const size_t bch = ((size_t)(b * 16 + c) * 32 + h) * 256;
    dt_out[bch + i]   = dtv;
    acum_out[bch + i] = val;
}

// ---------------------------------------------------------------------------
// xdtT: per (b,c,h) transpose of (x*dt) chunk -> xdtT[b,c,h,p,j] bf16
// ---------------------------------------------------------------------------
__global__ __launch_bounds__(256) void xdtt_kernel(
    const __bf16* __restrict__ xbf, const float* __restrict__ dtb,
    __bf16* __restrict__ xdtT)
{
    const int h = blockIdx.x, c = blockIdx.y, b = blockIdx.z;
    const size_t bc = (size_t)b * 16 + c;
    const size_t bch = bc * 32 + h;
    __shared__ __attribute__((aligned(16))) __bf16 tile[256][40];
    __shared__ float dts[256];
    const int t = threadIdx.x;
    dts[t] = dtb[bch * 256 + t];
    __syncthreads();
#pragma unroll
    for (int it = 0; it < 4; ++it) {
        int id = it * 256 + t;
        int j = id >> 2, pg = id & 3;
        bf16x8 v = *(const bf16x8*)&xbf[(bc * 256 + j) * 1024 + h * 32 + pg * 8];
        float d = dts[j];
        bf16x8 o;
#pragma unroll
        for (int e = 0; e < 8; ++e) o[e] = (__bf16)((float)v[e] * d);
        *(bf16x8*)&tile[j][pg * 8] = o;
    }
    __syncthreads();
#pragma unroll
    for (int it = 0; it < 4; ++it) {
        int id = it * 256 + t;
        int p = id >> 5, jg = id & 31;
        bf16x8 o;
#pragma unroll
        for (int e = 0; e < 8; ++e) o[e] = tile[jg * 8 + e][p];
        *(bf16x8*)&xdtT[bch * 8192 + p * 256 + jg * 8] = o;
    }
}

// ---------------------------------------------------------------------------
// states: per (b,c,h): states[p,n] = sum_j xdt[p,j] * B[j,n] * exp(alast-a_j)
// ---------------------------------------------------------------------------
__global__ __launch_bounds__(256) void states_kernel(
    const __bf16* __restrict__ Bbf, const float* __restrict__ acum,
    const __bf16* __restrict__ xdtT, float* __restrict__ states)
{
    const int h = blockIdx.x, c = blockIdx.y, b = blockIdx.z;
    const size_t bc = (size_t)b * 16 + c;
    const size_t bch = bc * 32 + h;
    __shared__ __attribute__((aligned(16))) __bf16 Bsh[256 * 64];
    __shared__ __attribute__((aligned(16))) __bf16 BdT[64][264];
    __shared__ float decs[256];
    __shared__ float alast_sh;
    const int t = threadIdx.x, wave = t >> 6, lane = t & 63;

    const __bf16* Bsrc = Bbf + bc * 16384;
#pragma unroll
    for (int cc = 0; cc < 8; ++cc) {
        int s = wave * 8 + cc;
        int row = s * 8 + (lane >> 3);
        async_copy16(Bsrc + row * 64 + (lane & 7) * 8, Bsh + s * 512);
    }
    float a = acum[bch * 256 + t];
    if (t == 255) alast_sh = a;
    __syncthreads();
    decs[t] = __expf(alast_sh - a);
    __syncthreads();
    for (int idx = t; idx < 256 * 64; idx += 256) {
        int j = idx >> 6, n = idx & 63;
        BdT[n][j] = (__bf16)((float)Bsh[j * 64 + n] * decs[j]);
    }
    __syncthreads();
    const int fr = lane & 15, fk = (lane >> 4) * 8;
    const int mt  = wave >> 1;
    const int ntb = (wave & 1) * 2;
    f32x4 acc[2] = {};
    const __bf16* xrow = xdtT + bch * 8192;
#pragma unroll
    for (int ks = 0; ks < 8; ++ks) {
        bf16x8 af = *(const bf16x8*)&xrow[(mt * 16 + fr) * 256 + ks * 32 + fk];
#pragma unroll
        for (int nb = 0; nb < 2; ++nb) {
            bf16x8 bfv = *(const bf16x8*)&BdT[(ntb + nb) * 16 + fr][ks * 32 + fk];
            acc[nb] = MFMA16(af, bfv, acc[nb]);
        }
    }
    const int rowb = (lane >> 4) * 4;
#pragma unroll
    for (int nb = 0; nb < 2; ++nb)
#pragma unroll
        for (int q = 0; q < 4; ++q) {
            int p = mt * 16 + rowb + q;
            int n = (ntb + nb) * 16 + fr;
            states[bch * 2048 + p * 64 + n] = acc[nb][q];
        }
}

// ---------------------------------------------------------------------------
// scan: prev[b,c] = prev[b,c-1]*exp(alast[c-1]) + states[c-1]; bf16 out.
// ---------------------------------------------------------------------------
__global__ void scan_kernel(const float* __restrict__ states,
                            const float* __restrict__ acum,
                            __bf16* __restrict__ prevbf)
{
    int t = blockIdx.x * 256 + threadIdx.x;
    int n = t & 63, p = (t >> 6) & 31, h = (t >> 11) & 31, b = t >> 16;
    float s = 0.f;
    for (int c = 0; c < 16; ++c) {
        size_t bch = ((size_t)(b * 16 + c) * 32 + h);
        size_t off = bch * 2048 + (size_t)p * 64 + n;
        prevbf[off] = (__bf16)s;
        float dec = __expf(acum[bch * 256 + 255]);
        s = s * dec + states[off];
    }
}

// ---------------------------------------------------------------------------
// y: block=(b,c,h); 4 waves; wave w owns row-subtiles {w, w+4, w+8, w+12}.
// ---------------------------------------------------------------------------
__global__ __launch_bounds__(256, 2) void y_kernel(
    const __bf16* __restrict__ Bbf, const __bf16* __restrict__ Cbf,
    const float* __restrict__ acum, const __bf16* __restrict__ xdtT,
    const __bf16* __restrict__ prevbf, const __bf16* __restrict__ xbf,
    const float* __restrict__ Dp, __bf16* __restrict__ ybf)
{
    const int bidx = blockIdx.x;
    const int bc = bidx & 31, h = bidx >> 5;
    const size_t bch = (size_t)bc * 32 + h;
    __shared__ __attribute__((aligned(16))) __bf16 Bsh[256 * 64];
    __shared__ __attribute__((aligned(16))) __bf16 xsh[32 * 256];
    __shared__ __attribute__((aligned(16))) __bf16 Gw[4][16 * 72];
    __shared__ float ash[256];
    const int t = threadIdx.x, w = t >> 6, lane = t & 63;
    const int fr = lane & 15, q = lane >> 4;

    const __bf16* Bsrc = Bbf + (size_t)bc * 16384;
#pragma unroll
    for (int cc = 0; cc < 8; ++cc) {
        int s = w * 8 + cc;
        int row = s * 8 + (lane >> 3);
        int ch = (lane & 7) ^ ((lane >> 3) & 7);
        async_copy16(Bsrc + row * 64 + ch * 8, Bsh + s * 512);
    }
    const __bf16* xsrc = xdtT + bch * 8192;
#pragma unroll
    for (int cc = 0; cc < 4; ++cc) {
        int s = w * 4 + cc;
        int p = s * 2 + (lane >> 5);
        int cl = lane & 31;
        int ch = (cl & 24) | ((cl & 7) ^ (p & 7));
        async_copy16(xsrc + p * 256 + ch * 8, xsh + s * 512);
    }
    ash[t] = acum[bch * 256 + t];
    __syncthreads();

    bf16x8 cf[4][2], pf[2][2];
    float ei4[4];
#pragma unroll
    for (int s4 = 0; s4 < 4; ++s4) {
        int i = (w + 4 * s4) * 16 + fr;
        const __bf16* cp = Cbf + ((size_t)bc * 256 + i) * 64 + q * 8;
        cf[s4][0] = *(const bf16x8*)cp;
        cf[s4][1] = *(const bf16x8*)(cp + 32);
        ei4[s4] = __expf(ash[i]);
    }
#pragma unroll
    for (int mt = 0; mt < 2; ++mt) {
        const __bf16* pp = prevbf + bch * 2048 + (size_t)(mt * 16 + fr) * 64 + q * 8;
        pf[mt][0] = *(const bf16x8*)pp;
        pf[mt][1] = *(const bf16x8*)(pp + 32);
    }
    float ai[4][4];
#pragma unroll
    for (int s4 = 0; s4 < 4; ++s4)
#pragma unroll
        for (int r = 0; r < 4; ++r)
            ai[s4][r] = ash[(w + 4 * s4) * 16 + q * 4 + r];

    f32x4 acc[4][2] = {};

#pragma unroll
    for (int jt = 0; jt < 4; ++jt) {
        bf16x8 bb[4][2], xa[2][2];
#pragma unroll
        for (int nt = 0; nt < 4; ++nt) {
            int j = jt * 64 + nt * 16 + fr;
#pragma unroll
            for (int ks = 0; ks < 2; ++ks) {
                int ch = (q + 4 * ks) ^ (fr & 7);
                bb[nt][ks] = *(const bf16x8*)&Bsh[j * 64 + ch * 8];
            }
        }
#pragma unroll
        for (int mt = 0; mt < 2; ++mt) {
            int p = mt * 16 + fr;
#pragma unroll
            for (int ks = 0; ks < 2; ++ks) {
                int ch = 8 * jt + ((q + 4 * ks) ^ (p & 7));
                xa[mt][ks] = *(const bf16x8*)&xsh[p * 256 + ch * 8];
            }
        }
#pragma unroll
        for (int s4 = 0; s4 < 4; ++s4) {
            int si = w + 4 * s4;
            if (si < 4 * jt) continue;
            f32x4 sreg[4];
#pragma unroll
            for (int nt = 0; nt < 4; ++nt) {
                f32x4 z = {};
                z = MFMA16(cf[s4][0], bb[nt][0], z);
                z = MFMA16(cf[s4][1], bb[nt][1], z);
                sreg[nt] = z;
            }
#pragma unroll
            for (int nt = 0; nt < 4; ++nt) {
                int j = jt * 64 + nt * 16 + fr;
                float aj = ash[j];
#pragma unroll
                for (int r = 0; r < 4; ++r) {
                    int i = si * 16 + q * 4 + r;
                    float v = (j <= i) ? sreg[nt][r] * __expf(ai[s4][r] - aj) : 0.f;
                    Gw[w][(q * 4 + r) * 72 + nt * 16 + fr] = (__bf16)v;
                }
            }
            bf16x8 g0 = *(const bf16x8*)&Gw[w][fr * 72 + q * 8];
            bf16x8 g1 = *(const bf16x8*)&Gw[w][fr * 72 + 32 + q * 8];
#pragma unroll
            for (int mt = 0; mt < 2; ++mt) {
                acc[s4][mt] = MFMA16(xa[mt][0], g0, acc[s4][mt]);
                acc[s4][mt] = MFMA16(xa[mt][1], g1, acc[s4][mt]);
            }
        }
    }

#pragma unroll
    for (int s4 = 0; s4 < 4; ++s4) {
#pragma unroll
        for (int ks = 0; ks < 2; ++ks) {
            bf16x8 ce;
#pragma unroll
            for (int e = 0; e < 8; ++e)
                ce[e] = (__bf16)((float)cf[s4][ks][e] * ei4[s4]);
#pragma unroll
            for (int mt = 0; mt < 2; ++mt)
                acc[s4][mt] = MFMA16(pf[mt][ks], ce, acc[s4][mt]);
        }
    }

    const float Dv = Dp[h];
#pragma unroll
    for (int s4 = 0; s4 < 4; ++s4) {
        int i = (w + 4 * s4) * 16 + fr;
        size_t row = (size_t)bc * 256 + i;
#pragma unroll
        for (int mt = 0; mt < 2; ++mt) {
            int p0 = mt * 16 + q * 4;
            bf16x4 xv = *(const bf16x4*)&xbf[row * 1024 + h * 32 + p0];
            bf16x4 o;
#pragma unroll
            for (int e = 0; e < 4; ++e)
                o[e] = (__bf16)(acc[s4][mt][e] + (float)xv[e] * Dv);
            *(bf16x4*)&ybf[row * 1024 + h * 32 + p0] = o;
        }
    }
}

// ---------------------------------------------------------------------------
extern "C" void kernel_launch(void* const* d_in, const int* in_sizes, int n_in,
                              void* d_out, int out_size, void* d_ws, size_t ws_size,
                              hipStream_t stream)
{
    (void)in_sizes; (void)n_in; (void)out_size;
    const float* u       = (const float*)d_in[0];
    const float* W_in    = (const float*)d_in[1];
    const float* dt_bias = (const float*)d_in[2];
    const float* A_log   = (const float*)d_in[3];
    const float* Dp      = (const float*)d_in[4];
    const float* W_out   = (const float*)d_in[5];
    float* out = (float*)d_out;

    if (ws_size < 72679424) return;

    char* ws = (char*)d_ws;
    __bf16* u_bf    = (__bf16*)(ws);                  // 16,777,216 (reused as ybf)
    __bf16* win_bf  = (__bf16*)(ws + 16777216);       //  2,424,832
    __bf16* wout_bf = (__bf16*)(ws + 19202048);       //  2,097,152
    __bf16* xbf     = (__bf16*)(ws + 21299200);       // 16,777,216
    float*  dtz     = (float*) (ws + 38076416);       //  1,048,576
    float*  dtb     = (float*) (ws + 39124992);       //  1,048,576
    float*  acum    = (float*) (ws + 40173568);       //  1,048,576
    __bf16* xdtT    = (__bf16*)(ws + 41222144);       // 16,777,216
    float*  states  = (float*) (ws + 57999360);       //  8,388,608
    __bf16* prevbf  = (__bf16*)(ws + 66387968);       //  4,194,304
    __bf16* Bbf     = (__bf16*)(ws + 70582272);       //  1,048,576
    __bf16* Cbf     = (__bf16*)(ws + 71630848);       //  1,048,576

    cvt_f32_bf16<<<8192, 256, 0, stream>>>(u, u_bf, 8388608);
    cvt_f32_bf16<<<1184, 256, 0, stream>>>(W_in, win_bf, 1212416);
    cvt_f32_bf16<<<1024, 256, 0, stream>>>(W_out, wout_bf, 1048576);

    gemm_fused<<<dim3(64, 10), 256, 0, stream>>>(u_bf, win_bf, 1024, 1184, 1,
                                                 nullptr, xbf, Bbf, Cbf, dtz);

    prep_kernel<<<dim3(32, 16, 2), 256, 0, stream>>>(dtz, dt_bias, A_log, dtb, acum);
    xdtt_kernel<<<dim3(32, 16, 2), 256, 0, stream>>>(xbf, dtb, xdtT);
    states_kernel<<<dim3(32, 16, 2), 256, 0, stream>>>(Bbf, acum, xdtT, states);
    scan_kernel<<<512, 256, 0, stream>>>(states, acum, prevbf);

    __bf16* ybf = u_bf;  // u_bf dead after gemm1
    y_kernel<<<1024, 256, 0, stream>>>(Bbf, Cbf, acum, xdtT, prevbf,
                                       xbf, Dp, ybf);

    gemm_fused<<<dim3(64, 8), 256, 0, stream>>>(ybf, wout_bf, 1024, 1024, 0,
                                                out, nullptr, nullptr, nullptr, nullptr);
}

// Round 6
// 209.116 us; speedup vs baseline: 1.2215x; 1.1060x over previous
//
#include <hip/hip_runtime.h>
#include <hip/hip_bf16.h>
#include <stdint.h>

// ---------------------------------------------------------------------------
// SSD (Mamba-2 chunked scan) B=2, L=4096, DM=1024, NH=32, HD=32, DS=64, CS=256
// R6: BK=64 gemm K-loop (half the barriers), fused middle kernel
// (prep+xdtt+states, decay folded into x side, BbfT from gemm1 epilogue),
// single fused cvt kernel.
// ---------------------------------------------------------------------------

typedef __bf16 bf16x8 __attribute__((ext_vector_type(8)));
typedef __bf16 bf16x4 __attribute__((ext_vector_type(4)));
typedef float  f32x4  __attribute__((ext_vector_type(4)));

#define MFMA16(a, b, c) __builtin_amdgcn_mfma_f32_16x16x32_bf16((a), (b), (c), 0, 0, 0)

__device__ __forceinline__ void async_copy16(const __bf16* g, __bf16* l) {
    __builtin_amdgcn_global_load_lds((const __attribute__((address_space(1))) void*)g,
                                     (__attribute__((address_space(3))) void*)l,
                                     16, 0, 0);
}

// ---------------------------------------------------------------------------
// fused fp32->bf16 convert for u, W_in, W_out
// ---------------------------------------------------------------------------
__global__ void cvt_all(const float* __restrict__ u, __bf16* __restrict__ ub,
                        const float* __restrict__ wi, __bf16* __restrict__ wib,
                        const float* __restrict__ wo, __bf16* __restrict__ wob)
{
    long i = ((long)blockIdx.x * 256 + threadIdx.x) * 4;
    const float* src; __bf16* dst; long off;
    if (i < 8388608)        { src = u;  dst = ub;  off = i; }
    else if (i < 9601024)   { src = wi; dst = wib; off = i - 8388608; }
    else if (i < 10649600)  { src = wo; dst = wob; off = i - 9601024; }
    else return;
    float4 v = *(const float4*)(src + off);
    bf16x4 o;
    o[0] = (__bf16)v.x; o[1] = (__bf16)v.y; o[2] = (__bf16)v.z; o[3] = (__bf16)v.w;
    *(bf16x4*)(dst + off) = o;
}

// ---------------------------------------------------------------------------
// GEMM core: 128x128 tile, BK=64 (two 32-K slabs per barrier).
// LDS layout per slab: row*32 + p*8, position p holds chunk p ^ ((row&15)>>1&3).
// Staging: lane l -> row lr=l>>2, chunk (l&3)^((l>>3)&3) (coalesced 64B/row).
// Fragment read: pos = quad ^ ((fr>>1)&3)  => conflict-free (measured 0 in R5).
// mode 0: plain fp32 out. mode 1: routed epilogue (+BbfT transposed B copy).
// ---------------------------------------------------------------------------
__global__ __launch_bounds__(256) void gemm_fused(
    const __bf16* __restrict__ A, const __bf16* __restrict__ Bt,
    int K, int Nrows, int mode,
    float* __restrict__ Cout, __bf16* __restrict__ xbf,
    __bf16* __restrict__ Bbf, __bf16* __restrict__ Cbf,
    __bf16* __restrict__ BbfT, float* __restrict__ dtz)
{
    __shared__ __attribute__((aligned(16))) __bf16 As[8192];  // 2 slabs x 4096
    __shared__ __attribute__((aligned(16))) __bf16 Bs[8192];
    const int tid = threadIdx.x;
    const int m0 = blockIdx.x * 128;       // M-fast: same-A blocks share XCD
    const int n0 = blockIdx.y * 128;
    const int w = tid >> 6, lane = tid & 63;
    const int wm = w >> 1, wn = w & 1;
    const int fr = lane & 15, quad = lane >> 4;
    const int sw = quad ^ ((fr >> 1) & 3);         // fragment-read position

    const int lr  = lane >> 2;                      // row within 16-row group
    const int lc8 = (((lane & 3) ^ ((lane >> 3) & 3))) * 8;  // swizzled chunk
    const int ra0 = m0 + w * 32 + lr;
    const int rb0 = min(n0 + w * 32 + lr, Nrows - 1);
    const int rb1 = min(n0 + w * 32 + 16 + lr, Nrows - 1);
    const __bf16* aB0 = A + (size_t)ra0 * K + lc8;
    const __bf16* aB1 = A + (size_t)(ra0 + 16) * K + lc8;
    const __bf16* bB0 = Bt + (size_t)rb0 * K + lc8;
    const __bf16* bB1 = Bt + (size_t)rb1 * K + lc8;
    __bf16* dA = As + w * 1024;
    __bf16* dB = Bs + w * 1024;

    f32x4 acc[4][4] = {};

    for (int kt = 0; kt < K; kt += 64) {
#pragma unroll
        for (int s = 0; s < 2; ++s) {
            async_copy16(aB0 + kt + s * 32, dA + s * 4096);
            async_copy16(aB1 + kt + s * 32, dA + s * 4096 + 512);
            async_copy16(bB0 + kt + s * 32, dB + s * 4096);
            async_copy16(bB1 + kt + s * 32, dB + s * 4096 + 512);
        }
        __syncthreads();
#pragma unroll
        for (int s = 0; s < 2; ++s) {
            bf16x8 af[4], bfv[4];
#pragma unroll
            for (int a = 0; a < 4; ++a)
                af[a] = *(const bf16x8*)&As[s * 4096 + (wm * 64 + a * 16 + fr) * 32 + sw * 8];
#pragma unroll
            for (int b = 0; b < 4; ++b)
                bfv[b] = *(const bf16x8*)&Bs[s * 4096 + (wn * 64 + b * 16 + fr) * 32 + sw * 8];
#pragma unroll
            for (int a = 0; a < 4; ++a)
#pragma unroll
                for (int b = 0; b < 4; ++b)
                    acc[a][b] = MFMA16(af[a], bfv[b], acc[a][b]);
        }
        __syncthreads();
    }

    const int rowb = quad * 4;
    if (mode == 0) {
#pragma unroll
        for (int a = 0; a < 4; ++a)
#pragma unroll
            for (int b = 0; b < 4; ++b) {
                int col = n0 + wn * 64 + b * 16 + fr;
#pragma unroll
                for (int q = 0; q < 4; ++q) {
                    int row = m0 + wm * 64 + a * 16 + rowb + q;
                    Cout[(size_t)row * 1024 + col] = acc[a][b][q];
                }
            }
    } else if (blockIdx.y < 8) {
#pragma unroll
        for (int a = 0; a < 4; ++a)
#pragma unroll
            for (int b = 0; b < 4; ++b) {
                int col = n0 + wn * 64 + b * 16 + fr;
#pragma unroll
                for (int q = 0; q < 4; ++q) {
                    int row = m0 + wm * 64 + a * 16 + rowb + q;
                    xbf[(size_t)row * 1024 + col] = (__bf16)acc[a][b][q];
                }
            }
    } else if (blockIdx.y == 8) {
#pragma unroll
        for (int a = 0; a < 4; ++a)
#pragma unroll
            for (int b = 0; b < 4; ++b) {
                int cl = wn * 64 + b * 16 + fr;
#pragma unroll
                for (int q = 0; q < 4; ++q) {
                    int row = m0 + wm * 64 + a * 16 + rowb + q;
                    __bf16 v = (__bf16)acc[a][b][q];
                    if (cl < 64) {
                        Bbf[(size_t)row * 64 + cl] = v;
                        // transposed copy for states: BbfT[bc][n][j]
                        BbfT[(size_t)(row >> 8) * 16384 + cl * 256 + (row & 255)] = v;
                    } else {
                        Cbf[(size_t)row * 64 + cl - 64] = v;
                    }
                }
            }
    } else {
#pragma unroll
        for (int a = 0; a < 4; ++a)
#pragma unroll
            for (int b = 0; b < 4; ++b) {
                int cl = wn * 64 + b * 16 + fr;
                if (cl < 32) {
#pragma unroll
                    for (int q = 0; q < 4; ++q) {
                        int row = m0 + wm * 64 + a * 16 + rowb + q;
                        dtz[(size_t)row * 32 + cl] = acc[a][b][q];
                    }
                }
            }
    }
}

// ---------------------------------------------------------------------------
// middle: per (b,c,h) fused prep + xdtT + states.
//  1. dt = softplus(dtz+bias), a = dt*A, LDS inclusive scan -> acum.
//  2. tile[j][p] = x*dt (stride-33: 4-way gather conflict, best possible).
//  3. transpose -> xdtT global (for y) + xdecT = x*dt*exp(alast-a_j) in LDS.
//  4. states[p,n] = sum_j xdecT[p,j] * BbfT[n,j]  (MFMA, B staged+swizzled).
// ---------------------------------------------------------------------------
__global__ __launch_bounds__(256) void middle_kernel(
    const float* __restrict__ dtz, const float* __restrict__ dt_bias,
    const float* __restrict__ A_log, const __bf16* __restrict__ xbf,
    const __bf16* __restrict__ BbfT,
    float* __restrict__ acum_out, __bf16* __restrict__ xdtT,
    float* __restrict__ states)
{
    const int h = blockIdx.x, c = blockIdx.y, b = blockIdx.z;
    const size_t bc = (size_t)b * 16 + c;
    const size_t bch = bc * 32 + h;
    __shared__ __bf16 tile[256][33];                                // 16.9 KB
    __shared__ __attribute__((aligned(16))) __bf16 xdecT[32 * 264]; // 16.9 KB
    __shared__ __attribute__((aligned(16))) __bf16 Bsh2[64 * 256];  // 32 KB
    __shared__ float buf[256], dts[256], decs[256];
    const int t = threadIdx.x, wave = t >> 6, lane = t & 63;

    // async stage BbfT[bc] (32 KB), chunk swizzled: pos p holds chunk p^(n&7)
    {
        const __bf16* src = BbfT + bc * 16384;
#pragma unroll
        for (int cc = 0; cc < 8; ++cc) {
            int s = wave * 8 + cc;
            int n = s * 2 + (lane >> 5);
            int jc = (lane & 31) ^ (n & 7);
            async_copy16(src + n * 256 + jc * 8, Bsh2 + s * 512);
        }
    }

    // --- prep: softplus + cumsum
    float z = dtz[(bc * 256 + t) * 32 + h] + dt_bias[h];
    float dtv = (z > 20.f) ? z : log1pf(expf(z));
    float Av = -expf(A_log[h]);
    float val = dtv * Av;
    dts[t] = dtv;
    buf[t] = val;
    __syncthreads();
#pragma unroll
    for (int off = 1; off < 256; off <<= 1) {
        float add = (t >= off) ? buf[t - off] : 0.f;
        __syncthreads();
        val += add;
        buf[t] = val;
        __syncthreads();
    }
    acum_out[bch * 256 + t] = val;
    float alast = buf[255];
    decs[t] = __expf(alast - val);

    // --- tile = x * dt   (j-major)
#pragma unroll
    for (int it = 0; it < 4; ++it) {
        int id = it * 256 + t;
        int j = id >> 2, pg = id & 3;
        bf16x8 v = *(const bf16x8*)&xbf[(bc * 256 + j) * 1024 + h * 32 + pg * 8];
        float d = dts[j];
#pragma unroll
        for (int e = 0; e < 8; ++e) tile[j][pg * 8 + e] = (__bf16)((float)v[e] * d);
    }
    __syncthreads();

    // --- transpose: xdtT global + decayed xdecT LDS
#pragma unroll
    for (int it = 0; it < 4; ++it) {
        int id = it * 256 + t;
        int p = id >> 5, jg = id & 31;
        bf16x8 o, od;
#pragma unroll
        for (int e = 0; e < 8; ++e) {
            __bf16 v = tile[jg * 8 + e][p];
            o[e] = v;
            od[e] = (__bf16)((float)v * decs[jg * 8 + e]);
        }
        *(bf16x8*)&xdtT[bch * 8192 + p * 256 + jg * 8] = o;
        *(bf16x8*)&xdecT[p * 264 + jg * 8] = od;
    }
    __syncthreads();

    // --- states MFMA: M=32(p), N=64(n), K=256(j)
    const int fr = lane & 15, quad = lane >> 4, fk = quad * 8;
    const int mt = wave >> 1, ntb = (wave & 1) * 2;
    f32x4 acc[2] = {};
#pragma unroll
    for (int ks = 0; ks < 8; ++ks) {
        bf16x8 af = *(const bf16x8*)&xdecT[(mt * 16 + fr) * 264 + ks * 32 + fk];
#pragma unroll
        for (int nb = 0; nb < 2; ++nb) {
            int n = (ntb + nb) * 16 + fr;
            int ch = (ks * 4 + quad) ^ (n & 7);
            bf16x8 bfv = *(const bf16x8*)&Bsh2[n * 256 + ch * 8];
            acc[nb] = MFMA16(af, bfv, acc[nb]);
        }
    }
    const int rowb = quad * 4;
#pragma unroll
    for (int nb = 0; nb < 2; ++nb)
#pragma unroll
        for (int q = 0; q < 4; ++q) {
            int p = mt * 16 + rowb + q;
            int n = (ntb + nb) * 16 + fr;
            states[bch * 2048 + p * 64 + n] = acc[nb][q];
        }
}

// ---------------------------------------------------------------------------
// scan: prev[b,c] = prev[b,c-1]*exp(alast[c-1]) + states[c-1]; bf16 out.
// ---------------------------------------------------------------------------
__global__ void scan_kernel(const float* __restrict__ states,
                            const float* __restrict__ acum,
                            __bf16* __restrict__ prevbf)
{
    int t = blockIdx.x * 256 + threadIdx.x;
    int n = t & 63, p = (t >> 6) & 31, h = (t >> 11) & 31, b = t >> 16;
    float s = 0.f;
    for (int c = 0; c < 16; ++c) {
        size_t bch = ((size_t)(b * 16 + c) * 32 + h);
        size_t off = bch * 2048 + (size_t)p * 64 + n;
        prevbf[off] = (__bf16)s;
        float dec = __expf(acum[bch * 256 + 255]);
        s = s * dec + states[off];
    }
}

// ---------------------------------------------------------------------------
// y: block=(b,c,h); 4 waves; wave w owns row-subtiles {w, w+4, w+8, w+12}.
// ---------------------------------------------------------------------------
__global__ __launch_bounds__(256, 2) void y_kernel(
    const __bf16* __restrict__ Bbf, const __bf16* __restrict__ Cbf,
    const float* __restrict__ acum, const __bf16* __restrict__ xdtT,
    const __bf16* __restrict__ prevbf, const __bf16* __restrict__ xbf,
    const float* __restrict__ Dp, __bf16* __restrict__ ybf)
{
    const int bidx = blockIdx.x;
    const int bc = bidx & 31, h = bidx >> 5;
    const size_t bch = (size_t)bc * 32 + h;
    __shared__ __attribute__((aligned(16))) __bf16 Bsh[256 * 64];
    __shared__ __attribute__((aligned(16))) __bf16 xsh[32 * 256];
    __shared__ __attribute__((aligned(16))) __bf16 Gw[4][16 * 72];
    __shared__ float ash[256];
    const int t = threadIdx.x, w = t >> 6, lane = t & 63;
    const int fr = lane & 15, q = lane >> 4;

    const __bf16* Bsrc = Bbf + (size_t)bc * 16384;
#pragma unroll
    for (int cc = 0; cc < 8; ++cc) {
        int s = w * 8 + cc;
        int row = s * 8 + (lane >> 3);
        int ch = (lane & 7) ^ ((lane >> 3) & 7);
        async_copy16(Bsrc + row * 64 + ch * 8, Bsh + s * 512);
    }
    const __bf16* xsrc = xdtT + bch * 8192;
#pragma unroll
    for (int cc = 0; cc < 4; ++cc) {
        int s = w * 4 + cc;
        int p = s * 2 + (lane >> 5);
        int cl = lane & 31;
        int ch = (cl & 24) | ((cl & 7) ^ (p & 7));
        async_copy16(xsrc + p * 256 + ch * 8, xsh + s * 512);
    }
    ash[t] = acum[bch * 256 + t];
    __syncthreads();

    bf16x8 cf[4][2], pf[2][2];
    float ei4[4];
#pragma unroll
    for (int s4 = 0; s4 < 4; ++s4) {
        int i = (w + 4 * s4) * 16 + fr;
        const __bf16* cp = Cbf + ((size_t)bc * 256 + i) * 64 + q * 8;
        cf[s4][0] = *(const bf16x8*)cp;
        cf[s4][1] = *(const bf16x8*)(cp + 32);
        ei4[s4] = __expf(ash[i]);
    }
#pragma unroll
    for (int mt = 0; mt < 2; ++mt) {
        const __bf16* pp = prevbf + bch * 2048 + (size_t)(mt * 16 + fr) * 64 + q * 8;
        pf[mt][0] = *(const bf16x8*)pp;
        pf[mt][1] = *(const bf16x8*)(pp + 32);
    }
    float ai[4][4];
#pragma unroll
    for (int s4 = 0; s4 < 4; ++s4)
#pragma unroll
        for (int r = 0; r < 4; ++r)
            ai[s4][r] = ash[(w + 4 * s4) * 16 + q * 4 + r];

    f32x4 acc[4][2] = {};

#pragma unroll
    for (int jt = 0; jt < 4; ++jt) {
        bf16x8 bb[4][2], xa[2][2];
#pragma unroll
        for (int nt = 0; nt < 4; ++nt) {
            int j = jt * 64 + nt * 16 + fr;
#pragma unroll
            for (int ks = 0; ks < 2; ++ks) {
                int ch = (q + 4 * ks) ^ (fr & 7);
                bb[nt][ks] = *(const bf16x8*)&Bsh[j * 64 + ch * 8];
            }
        }
#pragma unroll
        for (int mt = 0; mt < 2; ++mt) {
            int p = mt * 16 + fr;
#pragma unroll
            for (int ks = 0; ks < 2; ++ks) {
                int ch = 8 * jt + ((q + 4 * ks) ^ (p & 7));
                xa[mt][ks] = *(const bf16x8*)&xsh[p * 256 + ch * 8];
            }
        }
#pragma unroll
        for (int s4 = 0; s4 < 4; ++s4) {
            int si = w + 4 * s4;
            if (si < 4 * jt) continue;
            f32x4 sreg[4];
#pragma unroll
            for (int nt = 0; nt < 4; ++nt) {
                f32x4 z = {};
                z = MFMA16(cf[s4][0], bb[nt][0], z);
                z = MFMA16(cf[s4][1], bb[nt][1], z);
                sreg[nt] = z;
            }
#pragma unroll
            for (int nt = 0; nt < 4; ++nt) {
                int j = jt * 64 + nt * 16 + fr;
                float aj = ash[j];
#pragma unroll
                for (int r = 0; r < 4; ++r) {
                    int i = si * 16 + q * 4 + r;
                    float v = (j <= i) ? sreg[nt][r] * __expf(ai[s4][r] - aj) : 0.f;
                    Gw[w][(q * 4 + r) * 72 + nt * 16 + fr] = (__bf16)v;
                }
            }
            bf16x8 g0 = *(const bf16x8*)&Gw[w][fr * 72 + q * 8];
            bf16x8 g1 = *(const bf16x8*)&Gw[w][fr * 72 + 32 + q * 8];
#pragma unroll
            for (int mt = 0; mt < 2; ++mt) {
                acc[s4][mt] = MFMA16(xa[mt][0], g0, acc[s4][mt]);
                acc[s4][mt] = MFMA16(xa[mt][1], g1, acc[s4][mt]);
            }
        }
    }

#pragma unroll
    for (int s4 = 0; s4 < 4; ++s4) {
#pragma unroll
        for (int ks = 0; ks < 2; ++ks) {
            bf16x8 ce;
#pragma unroll
            for (int e = 0; e < 8; ++e)
                ce[e] = (__bf16)((float)cf[s4][ks][e] * ei4[s4]);
#pragma unroll
            for (int mt = 0; mt < 2; ++mt)
                acc[s4][mt] = MFMA16(pf[mt][ks], ce, acc[s4][mt]);
        }
    }

    const float Dv = Dp[h];
#pragma unroll
    for (int s4 = 0; s4 < 4; ++s4) {
        int i = (w + 4 * s4) * 16 + fr;
        size_t row = (size_t)bc * 256 + i;
#pragma unroll
        for (int mt = 0; mt < 2; ++mt) {
            int p0 = mt * 16 + q * 4;
            bf16x4 xv = *(const bf16x4*)&xbf[row * 1024 + h * 32 + p0];
            bf16x4 o;
#pragma unroll
            for (int e = 0; e < 4; ++e)
                o[e] = (__bf16)(acc[s4][mt][e] + (float)xv[e] * Dv);
            *(bf16x4*)&ybf[row * 1024 + h * 32 + p0] = o;
        }
    }
}

// ---------------------------------------------------------------------------
extern "C" void kernel_launch(void* const* d_in, const int* in_sizes, int n_in,
                              void* d_out, int out_size, void* d_ws, size_t ws_size,
                              hipStream_t stream)
{
    (void)in_sizes; (void)n_in; (void)out_size;
    const float* u       = (const float*)d_in[0];
    const float* W_in    = (const float*)d_in[1];
    const float* dt_bias = (const float*)d_in[2];
    const float* A_log   = (const float*)d_in[3];
    const float* Dp      = (const float*)d_in[4];
    const float* W_out   = (const float*)d_in[5];
    float* out = (float*)d_out;

    if (ws_size < 72679424) return;

    char* ws = (char*)d_ws;
    __bf16* u_bf    = (__bf16*)(ws);                  // 16,777,216 (reused as ybf)
    __bf16* win_bf  = (__bf16*)(ws + 16777216);       //  2,424,832
    __bf16* wout_bf = (__bf16*)(ws + 19202048);       //  2,097,152
    __bf16* xbf     = (__bf16*)(ws + 21299200);       // 16,777,216
    float*  dtz     = (float*) (ws + 38076416);       //  1,048,576
    float*  acum    = (float*) (ws + 39124992);       //  1,048,576
    __bf16* xdtT    = (__bf16*)(ws + 40173568);       // 16,777,216
    float*  states  = (float*) (ws + 56950784);       //  8,388,608
    __bf16* prevbf  = (__bf16*)(ws + 65339392);       //  4,194,304
    __bf16* Bbf     = (__bf16*)(ws + 69533696);       //  1,048,576
    __bf16* Cbf     = (__bf16*)(ws + 70582272);       //  1,048,576
    __bf16* BbfT    = (__bf16*)(ws + 71630848);       //  1,048,576

    cvt_all<<<10400, 256, 0, stream>>>(u, u_bf, W_in, win_bf, W_out, wout_bf);

    gemm_fused<<<dim3(64, 10), 256, 0, stream>>>(u_bf, win_bf, 1024, 1184, 1,
                                                 nullptr, xbf, Bbf, Cbf, BbfT, dtz);

    middle_kernel<<<dim3(32, 16, 2), 256, 0, stream>>>(dtz, dt_bias, A_log, xbf,
                                                       BbfT, acum, xdtT, states);
    scan_kernel<<<512, 256, 0, stream>>>(states, acum, prevbf);

    __bf16* ybf = u_bf;  // u_bf dead after gemm1
    y_kernel<<<1024, 256, 0, stream>>>(Bbf, Cbf, acum, xdtT, prevbf,
                                       xbf, Dp, ybf);

    gemm_fused<<<dim3(64, 8), 256, 0, stream>>>(ybf, wout_bf, 1024, 1024, 0,
                                                out, nullptr, nullptr, nullptr,
                                                nullptr, nullptr);
}

// Round 7
// 206.812 us; speedup vs baseline: 1.2351x; 1.0111x over previous
//
#include <hip/hip_runtime.h>
#include <hip/hip_bf16.h>
#include <stdint.h>

// ---------------------------------------------------------------------------
// SSD (Mamba-2 chunked scan) B=2, L=4096, DM=1024, NH=32, HD=32, DS=64, CS=256
// R7: gemm back to BK=32 (R5's measured-best K-loop: 44us, 0 conflicts);
// BbfT produced via LDS transpose + coalesced writes (R6's 2B scatter caused
// +5MB RMW fetch traffic). Middle/scan/y unchanged from R6.
// ---------------------------------------------------------------------------

typedef __bf16 bf16x8 __attribute__((ext_vector_type(8)));
typedef __bf16 bf16x4 __attribute__((ext_vector_type(4)));
typedef float  f32x4  __attribute__((ext_vector_type(4)));

#define MFMA16(a, b, c) __builtin_amdgcn_mfma_f32_16x16x32_bf16((a), (b), (c), 0, 0, 0)

__device__ __forceinline__ void async_copy16(const __bf16* g, __bf16* l) {
    __builtin_amdgcn_global_load_lds((const __attribute__((address_space(1))) void*)g,
                                     (__attribute__((address_space(3))) void*)l,
                                     16, 0, 0);
}

// ---------------------------------------------------------------------------
// fused fp32->bf16 convert for u, W_in, W_out
// ---------------------------------------------------------------------------
__global__ void cvt_all(const float* __restrict__ u, __bf16* __restrict__ ub,
                        const float* __restrict__ wi, __bf16* __restrict__ wib,
                        const float* __restrict__ wo, __bf16* __restrict__ wob)
{
    long i = ((long)blockIdx.x * 256 + threadIdx.x) * 4;
    const float* src; __bf16* dst; long off;
    if (i < 8388608)        { src = u;  dst = ub;  off = i; }
    else if (i < 9601024)   { src = wi; dst = wib; off = i - 8388608; }
    else if (i < 10649600)  { src = wo; dst = wob; off = i - 9601024; }
    else return;
    float4 v = *(const float4*)(src + off);
    bf16x4 o;
    o[0] = (__bf16)v.x; o[1] = (__bf16)v.y; o[2] = (__bf16)v.z; o[3] = (__bf16)v.w;
    *(bf16x4*)(dst + off) = o;
}

// ---------------------------------------------------------------------------
// GEMM core: 128x128 tile, BK=32 (R5 structure, measured 44us / 0 conflicts).
// LDS: row*32 + p*8, position p holds chunk p ^ ((fr>>1)&3) via staging lane
// map: lane l -> row l>>2, chunk (l&3)^((l>>3)&3) (coalesced 64B/row).
// mode 0: plain fp32 out. mode 1: routed epilogue; y==8 blocks also emit
// BbfT via LDS transpose (coalesced global writes).
// ---------------------------------------------------------------------------
__global__ __launch_bounds__(256) void gemm_fused(
    const __bf16* __restrict__ A, const __bf16* __restrict__ Bt,
    int K, int Nrows, int mode,
    float* __restrict__ Cout, __bf16* __restrict__ xbf,
    __bf16* __restrict__ Bbf, __bf16* __restrict__ Cbf,
    __bf16* __restrict__ BbfT, float* __restrict__ dtz)
{
    __shared__ __attribute__((aligned(16))) __bf16 smem[8704];
    __bf16* As = smem;            // 4096
    __bf16* Bs = smem + 4096;     // 4096
    const int tid = threadIdx.x;
    const int m0 = blockIdx.x * 128;       // M-fast: same-A blocks share XCD
    const int n0 = blockIdx.y * 128;
    const int w = tid >> 6, lane = tid & 63;
    const int wm = w >> 1, wn = w & 1;
    const int fr = lane & 15, quad = lane >> 4;
    const int sw = quad ^ ((fr >> 1) & 3);         // fragment-read position

    const int lr  = lane >> 2;                      // row within 16-row group
    const int lc8 = (((lane & 3) ^ ((lane >> 3) & 3))) * 8;  // swizzled chunk
    const int ra0 = m0 + w * 32 + lr;
    const int ra1 = ra0 + 16;
    const int rb0 = min(n0 + w * 32 + lr, Nrows - 1);
    const int rb1 = min(n0 + w * 32 + 16 + lr, Nrows - 1);
    const __bf16* aP0 = A + (size_t)ra0 * K + lc8;
    const __bf16* aP1 = A + (size_t)ra1 * K + lc8;
    const __bf16* bP0 = Bt + (size_t)rb0 * K + lc8;
    const __bf16* bP1 = Bt + (size_t)rb1 * K + lc8;
    __bf16* dA0 = As + w * 1024;
    __bf16* dA1 = As + w * 1024 + 512;
    __bf16* dB0 = Bs + w * 1024;
    __bf16* dB1 = Bs + w * 1024 + 512;

    f32x4 acc[4][4] = {};

    for (int kt = 0; kt < K; kt += 32) {
        async_copy16(aP0 + kt, dA0);
        async_copy16(aP1 + kt, dA1);
        async_copy16(bP0 + kt, dB0);
        async_copy16(bP1 + kt, dB1);
        __syncthreads();
        bf16x8 af[4], bfv[4];
#pragma unroll
        for (int a = 0; a < 4; ++a)
            af[a] = *(const bf16x8*)&As[(wm * 64 + a * 16 + fr) * 32 + sw * 8];
#pragma unroll
        for (int b = 0; b < 4; ++b)
            bfv[b] = *(const bf16x8*)&Bs[(wn * 64 + b * 16 + fr) * 32 + sw * 8];
#pragma unroll
        for (int a = 0; a < 4; ++a)
#pragma unroll
            for (int b = 0; b < 4; ++b)
                acc[a][b] = MFMA16(af[a], bfv[b], acc[a][b]);
        __syncthreads();
    }

    const int rowb = quad * 4;
    if (mode == 0) {
#pragma unroll
        for (int a = 0; a < 4; ++a)
#pragma unroll
            for (int b = 0; b < 4; ++b) {
                int col = n0 + wn * 64 + b * 16 + fr;
#pragma unroll
                for (int q = 0; q < 4; ++q) {
                    int row = m0 + wm * 64 + a * 16 + rowb + q;
                    Cout[(size_t)row * 1024 + col] = acc[a][b][q];
                }
            }
    } else if (blockIdx.y < 8) {
#pragma unroll
        for (int a = 0; a < 4; ++a)
#pragma unroll
            for (int b = 0; b < 4; ++b) {
                int col = n0 + wn * 64 + b * 16 + fr;
#pragma unroll
                for (int q = 0; q < 4; ++q) {
                    int row = m0 + wm * 64 + a * 16 + rowb + q;
                    xbf[(size_t)row * 1024 + col] = (__bf16)acc[a][b][q];
                }
            }
    } else if (blockIdx.y == 8) {
        // B/C routing + LDS-transposed coalesced BbfT
        __bf16* Btile = smem;   // 64 x 136 (K-loop done; smem free)
#pragma unroll
        for (int a = 0; a < 4; ++a)
#pragma unroll
            for (int b = 0; b < 4; ++b) {
                int cl = wn * 64 + b * 16 + fr;
#pragma unroll
                for (int q = 0; q < 4; ++q) {
                    int row = m0 + wm * 64 + a * 16 + rowb + q;
                    __bf16 v = (__bf16)acc[a][b][q];
                    if (cl < 64) {
                        Bbf[(size_t)row * 64 + cl] = v;
                        Btile[cl * 136 + (row - m0)] = v;
                    } else {
                        Cbf[(size_t)row * 64 + cl - 64] = v;
                    }
                }
            }
        __syncthreads();
        // coalesced BbfT[bc][n][j] writes: 64 n-rows x 128 j per block
        const size_t bcb = (size_t)(m0 >> 8) * 16384 + (m0 & 255);
        int n = tid >> 2, g = tid & 3;
#pragma unroll
        for (int it = 0; it < 4; ++it) {
            int jl = g * 32 + it * 8;
            bf16x8 v = *(const bf16x8*)&Btile[n * 136 + jl];
            *(bf16x8*)&BbfT[bcb + (size_t)n * 256 + jl] = v;
        }
    } else {
#pragma unroll
        for (int a = 0; a < 4; ++a)
#pragma unroll
            for (int b = 0; b < 4; ++b) {
                int cl = wn * 64 + b * 16 + fr;
                if (cl < 32) {
#pragma unroll
                    for (int q = 0; q < 4; ++q) {
                        int row = m0 + wm * 64 + a * 16 + rowb + q;
                        dtz[(size_t)row * 32 + cl] = acc[a][b][q];
                    }
                }
            }
    }
}

// ---------------------------------------------------------------------------
// middle: per (b,c,h) fused prep + xdtT + states (unchanged from R6).
// ---------------------------------------------------------------------------
__global__ __launch_bounds__(256) void middle_kernel(
    const float* __restrict__ dtz, const float* __restrict__ dt_bias,
    const float* __restrict__ A_log, const __bf16* __restrict__ xbf,
    const __bf16* __restrict__ BbfT,
    float* __restrict__ acum_out, __bf16* __restrict__ xdtT,
    float* __restrict__ states)
{
    const int h = blockIdx.x, c = blockIdx.y, b = blockIdx.z;
    const size_t bc = (size_t)b * 16 + c;
    const size_t bch = bc * 32 + h;
    __shared__ __bf16 tile[256][33];
    __shared__ __attribute__((aligned(16))) __bf16 xdecT[32 * 264];
    __shared__ __attribute__((aligned(16))) __bf16 Bsh2[64 * 256];
    __shared__ float buf[256], dts[256], decs[256];
    const int t = threadIdx.x, wave = t >> 6, lane = t & 63;

    {
        const __bf16* src = BbfT + bc * 16384;
#pragma unroll
        for (int cc = 0; cc < 8; ++cc) {
            int s = wave * 8 + cc;
            int n = s * 2 + (lane >> 5);
            int jc = (lane & 31) ^ (n & 7);
            async_copy16(src + n * 256 + jc * 8, Bsh2 + s * 512);
        }
    }

    float z = dtz[(bc * 256 + t) * 32 + h] + dt_bias[h];
    float dtv = (z > 20.f) ? z : log1pf(expf(z));
    float Av = -expf(A_log[h]);
    float val = dtv * Av;
    dts[t] = dtv;
    buf[t] = val;
    __syncthreads();
#pragma unroll
    for (int off = 1; off < 256; off <<= 1) {
        float add = (t >= off) ? buf[t - off] : 0.f;
        __syncthreads();
        val += add;
        buf[t] = val;
        __syncthreads();
    }
    acum_out[bch * 256 + t] = val;
    float alast = buf[255];
    decs[t] = __expf(alast - val);

#pragma unroll
    for (int it = 0; it < 4; ++it) {
        int id = it * 256 + t;
        int j = id >> 2, pg = id & 3;
        bf16x8 v = *(const bf16x8*)&xbf[(bc * 256 + j) * 1024 + h * 32 + pg * 8];
        float d = dts[j];
#pragma unroll
        for (int e = 0; e < 8; ++e) tile[j][pg * 8 + e] = (__bf16)((float)v[e] * d);
    }
    __syncthreads();

#pragma unroll
    for (int it = 0; it < 4; ++it) {
        int id = it * 256 + t;
        int p = id >> 5, jg = id & 31;
        bf16x8 o, od;
#pragma unroll
        for (int e = 0; e < 8; ++e) {
            __bf16 v = tile[jg * 8 + e][p];
            o[e] = v;
            od[e] = (__bf16)((float)v * decs[jg * 8 + e]);
        }
        *(bf16x8*)&xdtT[bch * 8192 + p * 256 + jg * 8] = o;
        *(bf16x8*)&xdecT[p * 264 + jg * 8] = od;
    }
    __syncthreads();

    const int fr = lane & 15, quad = lane >> 4, fk = quad * 8;
    const int mt = wave >> 1, ntb = (wave & 1) * 2;
    f32x4 acc[2] = {};
#pragma unroll
    for (int ks = 0; ks < 8; ++ks) {
        bf16x8 af = *(const bf16x8*)&xdecT[(mt * 16 + fr) * 264 + ks * 32 + fk];
#pragma unroll
        for (int nb = 0; nb < 2; ++nb) {
            int n = (ntb + nb) * 16 + fr;
            int ch = (ks * 4 + quad) ^ (n & 7);
            bf16x8 bfv = *(const bf16x8*)&Bsh2[n * 256 + ch * 8];
            acc[nb] = MFMA16(af, bfv, acc[nb]);
        }
    }
    const int rowb = quad * 4;
#pragma unroll
    for (int nb = 0; nb < 2; ++nb)
#pragma unroll
        for (int q = 0; q < 4; ++q) {
            int p = mt * 16 + rowb + q;
            int n = (ntb + nb) * 16 + fr;
            states[bch * 2048 + p * 64 + n] = acc[nb][q];
        }
}

// ---------------------------------------------------------------------------
// scan: prev[b,c] = prev[b,c-1]*exp(alast[c-1]) + states[c-1]; bf16 out.
// ---------------------------------------------------------------------------
__global__ void scan_kernel(const float* __restrict__ states,
                            const float* __restrict__ acum,
                            __bf16* __restrict__ prevbf)
{
    int t = blockIdx.x * 256 + threadIdx.x;
    int n = t & 63, p = (t >> 6) & 31, h = (t >> 11) & 31, b = t >> 16;
    float s = 0.f;
    for (int c = 0; c < 16; ++c) {
        size_t bch = ((size_t)(b * 16 + c) * 32 + h);
        size_t off = bch * 2048 + (size_t)p * 64 + n;
        prevbf[off] = (__bf16)s;
        float dec = __expf(acum[bch * 256 + 255]);
        s = s * dec + states[off];
    }
}

// ---------------------------------------------------------------------------
// y: block=(b,c,h); 4 waves; wave w owns row-subtiles {w, w+4, w+8, w+12}.
// ---------------------------------------------------------------------------
__global__ __launch_bounds__(256, 2) void y_kernel(
    const __bf16* __restrict__ Bbf, const __bf16* __restrict__ Cbf,
    const float* __restrict__ acum, const __bf16* __restrict__ xdtT,
    const __bf16* __restrict__ prevbf, const __bf16* __restrict__ xbf,
    const float* __restrict__ Dp, __bf16* __restrict__ ybf)
{
    const int bidx = blockIdx.x;
    const int bc = bidx & 31, h = bidx >> 5;
    const size_t bch = (size_t)bc * 32 + h;
    __shared__ __attribute__((aligned(16))) __bf16 Bsh[256 * 64];
    __shared__ __attribute__((aligned(16))) __bf16 xsh[32 * 256];
    __shared__ __attribute__((aligned(16))) __bf16 Gw[4][16 * 72];
    __shared__ float ash[256];
    const int t = threadIdx.x, w = t >> 6, lane = t & 63;
    const int fr = lane & 15, q = lane >> 4;

    const __bf16* Bsrc = Bbf + (size_t)bc * 16384;
#pragma unroll
    for (int cc = 0; cc < 8; ++cc) {
        int s = w * 8 + cc;
        int row = s * 8 + (lane >> 3);
        int ch = (lane & 7) ^ ((lane >> 3) & 7);
        async_copy16(Bsrc + row * 64 + ch * 8, Bsh + s * 512);
    }
    const __bf16* xsrc = xdtT + bch * 8192;
#pragma unroll
    for (int cc = 0; cc < 4; ++cc) {
        int s = w * 4 + cc;
        int p = s * 2 + (lane >> 5);
        int cl = lane & 31;
        int ch = (cl & 24) | ((cl & 7) ^ (p & 7));
        async_copy16(xsrc + p * 256 + ch * 8, xsh + s * 512);
    }
    ash[t] = acum[bch * 256 + t];
    __syncthreads();

    bf16x8 cf[4][2], pf[2][2];
    float ei4[4];
#pragma unroll
    for (int s4 = 0; s4 < 4; ++s4) {
        int i = (w + 4 * s4) * 16 + fr;
        const __bf16* cp = Cbf + ((size_t)bc * 256 + i) * 64 + q * 8;
        cf[s4][0] = *(const bf16x8*)cp;
        cf[s4][1] = *(const bf16x8*)(cp + 32);
        ei4[s4] = __expf(ash[i]);
    }
#pragma unroll
    for (int mt = 0; mt < 2; ++mt) {
        const __bf16* pp = prevbf + bch * 2048 + (size_t)(mt * 16 + fr) * 64 + q * 8;
        pf[mt][0] = *(const bf16x8*)pp;
        pf[mt][1] = *(const bf16x8*)(pp + 32);
    }
    float ai[4][4];
#pragma unroll
    for (int s4 = 0; s4 < 4; ++s4)
#pragma unroll
        for (int r = 0; r < 4; ++r)
            ai[s4][r] = ash[(w + 4 * s4) * 16 + q * 4 + r];

    f32x4 acc[4][2] = {};

#pragma unroll
    for (int jt = 0; jt < 4; ++jt) {
        bf16x8 bb[4][2], xa[2][2];
#pragma unroll
        for (int nt = 0; nt < 4; ++nt) {
            int j = jt * 64 + nt * 16 + fr;
#pragma unroll
            for (int ks = 0; ks < 2; ++ks) {
                int ch = (q + 4 * ks) ^ (fr & 7);
                bb[nt][ks] = *(const bf16x8*)&Bsh[j * 64 + ch * 8];
            }
        }
#pragma unroll
        for (int mt = 0; mt < 2; ++mt) {
            int p = mt * 16 + fr;
#pragma unroll
            for (int ks = 0; ks < 2; ++ks) {
                int ch = 8 * jt + ((q + 4 * ks) ^ (p & 7));
                xa[mt][ks] = *(const bf16x8*)&xsh[p * 256 + ch * 8];
            }
        }
#pragma unroll
        for (int s4 = 0; s4 < 4; ++s4) {
            int si = w + 4 * s4;
            if (si < 4 * jt) continue;
            f32x4 sreg[4];
#pragma unroll
            for (int nt = 0; nt < 4; ++nt) {
                f32x4 z = {};
                z = MFMA16(cf[s4][0], bb[nt][0], z);
                z = MFMA16(cf[s4][1], bb[nt][1], z);
                sreg[nt] = z;
            }
#pragma unroll
            for (int nt = 0; nt < 4; ++nt) {
                int j = jt * 64 + nt * 16 + fr;
                float aj = ash[j];
#pragma unroll
                for (int r = 0; r < 4; ++r) {
                    int i = si * 16 + q * 4 + r;
                    float v = (j <= i) ? sreg[nt][r] * __expf(ai[s4][r] - aj) : 0.f;
                    Gw[w][(q * 4 + r) * 72 + nt * 16 + fr] = (__bf16)v;
                }
            }
            bf16x8 g0 = *(const bf16x8*)&Gw[w][fr * 72 + q * 8];
            bf16x8 g1 = *(const bf16x8*)&Gw[w][fr * 72 + 32 + q * 8];
#pragma unroll
            for (int mt = 0; mt < 2; ++mt) {
                acc[s4][mt] = MFMA16(xa[mt][0], g0, acc[s4][mt]);
                acc[s4][mt] = MFMA16(xa[mt][1], g1, acc[s4][mt]);
            }
        }
    }

#pragma unroll
    for (int s4 = 0; s4 < 4; ++s4) {
#pragma unroll
        for (int ks = 0; ks < 2; ++ks) {
            bf16x8 ce;
#pragma unroll
            for (int e = 0; e < 8; ++e)
                ce[e] = (__bf16)((float)cf[s4][ks][e] * ei4[s4]);
#pragma unroll
            for (int mt = 0; mt < 2; ++mt)
                acc[s4][mt] = MFMA16(pf[mt][ks], ce, acc[s4][mt]);
        }
    }

    const float Dv = Dp[h];
#pragma unroll
    for (int s4 = 0; s4 < 4; ++s4) {
        int i = (w + 4 * s4) * 16 + fr;
        size_t row = (size_t)bc * 256 + i;
#pragma unroll
        for (int mt = 0; mt < 2; ++mt) {
            int p0 = mt * 16 + q * 4;
            bf16x4 xv = *(const bf16x4*)&xbf[row * 1024 + h * 32 + p0];
            bf16x4 o;
#pragma unroll
            for (int e = 0; e < 4; ++e)
                o[e] = (__bf16)(acc[s4][mt][e] + (float)xv[e] * Dv);
            *(bf16x4*)&ybf[row * 1024 + h * 32 + p0] = o;
        }
    }
}

// ---------------------------------------------------------------------------
extern "C" void kernel_launch(void* const* d_in, const int* in_sizes, int n_in,
                              void* d_out, int out_size, void* d_ws, size_t ws_size,
                              hipStream_t stream)
{
    (void)in_sizes; (void)n_in; (void)out_size;
    const float* u       = (const float*)d_in[0];
    const float* W_in    = (const float*)d_in[1];
    const float* dt_bias = (const float*)d_in[2];
    const float* A_log   = (const float*)d_in[3];
    const float* Dp      = (const float*)d_in[4];
    const float* W_out   = (const float*)d_in[5];
    float* out = (float*)d_out;

    if (ws_size < 72679424) return;

    char* ws = (char*)d_ws;
    __bf16* u_bf    = (__bf16*)(ws);                  // 16,777,216 (reused as ybf)
    __bf16* win_bf  = (__bf16*)(ws + 16777216);       //  2,424,832
    __bf16* wout_bf = (__bf16*)(ws + 19202048);       //  2,097,152
    __bf16* xbf     = (__bf16*)(ws + 21299200);       // 16,777,216
    float*  dtz     = (float*) (ws + 38076416);       //  1,048,576
    float*  acum    = (float*) (ws + 39124992);       //  1,048,576
    __bf16* xdtT    = (__bf16*)(ws + 40173568);       // 16,777,216
    float*  states  = (float*) (ws + 56950784);       //  8,388,608
    __bf16* prevbf  = (__bf16*)(ws + 65339392);       //  4,194,304
    __bf16* Bbf     = (__bf16*)(ws + 69533696);       //  1,048,576
    __bf16* Cbf     = (__bf16*)(ws + 70582272);       //  1,048,576
    __bf16* BbfT    = (__bf16*)(ws + 71630848);       //  1,048,576

    cvt_all<<<10400, 256, 0, stream>>>(u, u_bf, W_in, win_bf, W_out, wout_bf);

    gemm_fused<<<dim3(64, 10), 256, 0, stream>>>(u_bf, win_bf, 1024, 1184, 1,
                                                 nullptr, xbf, Bbf, Cbf, BbfT, dtz);

    middle_kernel<<<dim3(32, 16, 2), 256, 0, stream>>>(dtz, dt_bias, A_log, xbf,
                                                       BbfT, acum, xdtT, states);
    scan_kernel<<<512, 256, 0, stream>>>(states, acum, prevbf);

    __bf16* ybf = u_bf;  // u_bf dead after gemm1
    y_kernel<<<1024, 256, 0, stream>>>(Bbf, Cbf, acum, xdtT, prevbf,
                                       xbf, Dp, ybf);

    gemm_fused<<<dim3(64, 8), 256, 0, stream>>>(ybf, wout_bf, 1024, 1024, 0,
                                                out, nullptr, nullptr, nullptr,
                                                nullptr, nullptr);
}

// Round 8
// 205.452 us; speedup vs baseline: 1.2433x; 1.0066x over previous
//
#include <hip/hip_runtime.h>
#include <hip/hip_bf16.h>
#include <stdint.h>

// ---------------------------------------------------------------------------
// SSD (Mamba-2 chunked scan) B=2, L=4096, DM=1024, NH=32, HD=32, DS=64, CS=256
// R8: gemm tiles 64Mx128N (grid 2x: 5/4 blocks per CU vs 2.5/2 — the gemm was
// grid-limited: occupancy 18% w/ caps at 6 blocks/CU). Same R5/R7 swizzle
// (fragment rows stay 16-aligned so pos=quad^((fr>>1)&3) still yields chunk=
// quad). middle: wave-shuffle scan (2 barriers instead of 16).
// ---------------------------------------------------------------------------

typedef __bf16 bf16x8 __attribute__((ext_vector_type(8)));
typedef __bf16 bf16x4 __attribute__((ext_vector_type(4)));
typedef float  f32x4  __attribute__((ext_vector_type(4)));

#define MFMA16(a, b, c) __builtin_amdgcn_mfma_f32_16x16x32_bf16((a), (b), (c), 0, 0, 0)

__device__ __forceinline__ void async_copy16(const __bf16* g, __bf16* l) {
    __builtin_amdgcn_global_load_lds((const __attribute__((address_space(1))) void*)g,
                                     (__attribute__((address_space(3))) void*)l,
                                     16, 0, 0);
}

// ---------------------------------------------------------------------------
// fused fp32->bf16 convert for u, W_in, W_out
// ---------------------------------------------------------------------------
__global__ void cvt_all(const float* __restrict__ u, __bf16* __restrict__ ub,
                        const float* __restrict__ wi, __bf16* __restrict__ wib,
                        const float* __restrict__ wo, __bf16* __restrict__ wob)
{
    long i = ((long)blockIdx.x * 256 + threadIdx.x) * 4;
    const float* src; __bf16* dst; long off;
    if (i < 8388608)        { src = u;  dst = ub;  off = i; }
    else if (i < 9601024)   { src = wi; dst = wib; off = i - 8388608; }
    else if (i < 10649600)  { src = wo; dst = wob; off = i - 9601024; }
    else return;
    float4 v = *(const float4*)(src + off);
    bf16x4 o;
    o[0] = (__bf16)v.x; o[1] = (__bf16)v.y; o[2] = (__bf16)v.z; o[3] = (__bf16)v.w;
    *(bf16x4*)(dst + off) = o;
}

// ---------------------------------------------------------------------------
// GEMM core: 64M x 128N tile, BK=32.  4 waves; wave w owns N-cols
// [n0+w*32, +32) x all 64 M rows.  acc[4][2] per wave.
// LDS: As 64x32 (4KB) + Bs 128x32 (8KB), R5-swizzled:
//   staging lane l -> row l>>2, pos l&3 holds chunk (l&3)^((l>>3)&3);
//   fragment read pos = quad^((fr>>1)&3) -> chunk = quad (k = quad*8).
// mode 0: fp32 out (N=1024). mode 1: routed epilogue (+BbfT via LDS transp).
// ---------------------------------------------------------------------------
__global__ __launch_bounds__(256) void gemm_fused(
    const __bf16* __restrict__ A, const __bf16* __restrict__ Bt,
    int K, int Nrows, int mode,
    float* __restrict__ Cout, __bf16* __restrict__ xbf,
    __bf16* __restrict__ Bbf, __bf16* __restrict__ Cbf,
    __bf16* __restrict__ BbfT, float* __restrict__ dtz)
{
    __shared__ __attribute__((aligned(16))) __bf16 smem[6144];
    __bf16* As = smem;            // 64*32 = 2048
    __bf16* Bs = smem + 2048;     // 128*32 = 4096
    const int tid = threadIdx.x;
    const int m0 = blockIdx.x * 64;        // M-fast: same-A blocks share XCD
    const int n0 = blockIdx.y * 128;
    const int w = tid >> 6, lane = tid & 63;
    const int fr = lane & 15, quad = lane >> 4;
    const int sw = quad ^ ((fr >> 1) & 3);         // fragment-read position

    const int lr  = lane >> 2;                      // row within 16-row group
    const int lc8 = (((lane & 3) ^ ((lane >> 3) & 3))) * 8;  // swizzled chunk
    const int ra  = m0 + w * 16 + lr;               // A: wave stages 16 rows
    const int rb0 = min(n0 + w * 32 + lr, Nrows - 1);
    const int rb1 = min(n0 + w * 32 + 16 + lr, Nrows - 1);
    const __bf16* aP  = A + (size_t)ra * K + lc8;
    const __bf16* bP0 = Bt + (size_t)rb0 * K + lc8;
    const __bf16* bP1 = Bt + (size_t)rb1 * K + lc8;
    __bf16* dA  = As + w * 512;
    __bf16* dB0 = Bs + w * 1024;
    __bf16* dB1 = Bs + w * 1024 + 512;

    f32x4 acc[4][2] = {};

    for (int kt = 0; kt < K; kt += 32) {
        async_copy16(aP + kt, dA);
        async_copy16(bP0 + kt, dB0);
        async_copy16(bP1 + kt, dB1);
        __syncthreads();
        bf16x8 af[4], bfv[2];
#pragma unroll
        for (int a = 0; a < 4; ++a)
            af[a] = *(const bf16x8*)&As[(a * 16 + fr) * 32 + sw * 8];
#pragma unroll
        for (int b = 0; b < 2; ++b)
            bfv[b] = *(const bf16x8*)&Bs[(w * 32 + b * 16 + fr) * 32 + sw * 8];
#pragma unroll
        for (int a = 0; a < 4; ++a)
#pragma unroll
            for (int b = 0; b < 2; ++b)
                acc[a][b] = MFMA16(af[a], bfv[b], acc[a][b]);
        __syncthreads();
    }

    const int rowb = quad * 4;
    if (mode == 0) {
#pragma unroll
        for (int a = 0; a < 4; ++a)
#pragma unroll
            for (int b = 0; b < 2; ++b) {
                int col = n0 + w * 32 + b * 16 + fr;
#pragma unroll
                for (int q = 0; q < 4; ++q) {
                    int row = m0 + a * 16 + rowb + q;
                    Cout[(size_t)row * 1024 + col] = acc[a][b][q];
                }
            }
    } else if (blockIdx.y < 8) {
#pragma unroll
        for (int a = 0; a < 4; ++a)
#pragma unroll
            for (int b = 0; b < 2; ++b) {
                int col = n0 + w * 32 + b * 16 + fr;
#pragma unroll
                for (int q = 0; q < 4; ++q) {
                    int row = m0 + a * 16 + rowb + q;
                    xbf[(size_t)row * 1024 + col] = (__bf16)acc[a][b][q];
                }
            }
    } else if (blockIdx.y == 8) {
        // B/C routing + LDS-transposed coalesced BbfT (64 n x 64 rows)
        __bf16* Btile = smem;   // 64 x 72 (K-loop done; smem free)
#pragma unroll
        for (int a = 0; a < 4; ++a)
#pragma unroll
            for (int b = 0; b < 2; ++b) {
                int cl = w * 32 + b * 16 + fr;
#pragma unroll
                for (int q = 0; q < 4; ++q) {
                    int row = m0 + a * 16 + rowb + q;
                    __bf16 v = (__bf16)acc[a][b][q];
                    if (cl < 64) {
                        Bbf[(size_t)row * 64 + cl] = v;
                        Btile[cl * 72 + (row - m0)] = v;
                    } else {
                        Cbf[(size_t)row * 64 + cl - 64] = v;
                    }
                }
            }
        __syncthreads();
        const size_t bcb = (size_t)(m0 >> 8) * 16384 + (m0 & 255);
        int n = tid >> 2, g = tid & 3;
#pragma unroll
        for (int it = 0; it < 2; ++it) {
            int jl = g * 16 + it * 8;
            bf16x8 v = *(const bf16x8*)&Btile[n * 72 + jl];
            *(bf16x8*)&BbfT[bcb + (size_t)n * 256 + jl] = v;
        }
    } else {
#pragma unroll
        for (int a = 0; a < 4; ++a)
#pragma unroll
            for (int b = 0; b < 2; ++b) {
                int cl = w * 32 + b * 16 + fr;
                if (cl < 32) {
#pragma unroll
                    for (int q = 0; q < 4; ++q) {
                        int row = m0 + a * 16 + rowb + q;
                        dtz[(size_t)row * 32 + cl] = acc[a][b][q];
                    }
                }
            }
    }
}

// ---------------------------------------------------------------------------
// middle: per (b,c,h) fused prep + xdtT + states.
// R8: cumsum via wave-shuffle scan (2 barriers instead of 16).
// ---------------------------------------------------------------------------
__global__ __launch_bounds__(256) void middle_kernel(
    const float* __restrict__ dtz, const float* __restrict__ dt_bias,
    const float* __restrict__ A_log, const __bf16* __restrict__ xbf,
    const __bf16* __restrict__ BbfT,
    float* __restrict__ acum_out, __bf16* __restrict__ xdtT,
    float* __restrict__ states)
{
    const int h = blockIdx.x, c = blockIdx.y, b = blockIdx.z;
    const size_t bc = (size_t)b * 16 + c;
    const size_t bch = bc * 32 + h;
    __shared__ __bf16 tile[256][33];
    __shared__ __attribute__((aligned(16))) __bf16 xdecT[32 * 264];
    __shared__ __attribute__((aligned(16))) __bf16 Bsh2[64 * 256];
    __shared__ float dts[256], decs[256], wsum[4];
    const int t = threadIdx.x, wave = t >> 6, lane = t & 63;

    {
        const __bf16* src = BbfT + bc * 16384;
#pragma unroll
        for (int cc = 0; cc < 8; ++cc) {
            int s = wave * 8 + cc;
            int n = s * 2 + (lane >> 5);
            int jc = (lane & 31) ^ (n & 7);
            async_copy16(src + n * 256 + jc * 8, Bsh2 + s * 512);
        }
    }

    float z = dtz[(bc * 256 + t) * 32 + h] + dt_bias[h];
    float dtv = (z > 20.f) ? z : log1pf(expf(z));
    float Av = -expf(A_log[h]);
    float val = dtv * Av;
    dts[t] = dtv;
    // wave-level inclusive scan (no barriers)
#pragma unroll
    for (int off = 1; off < 64; off <<= 1) {
        float nv = __shfl_up(val, off, 64);
        if (lane >= off) val += nv;
    }
    if (lane == 63) wsum[wave] = val;
    __syncthreads();
    float basep = 0.f, tot = 0.f;
#pragma unroll
    for (int wv = 0; wv < 4; ++wv) {
        float s = wsum[wv];
        if (wv < wave) basep += s;
        tot += s;
    }
    val += basep;
    acum_out[bch * 256 + t] = val;
    decs[t] = __expf(tot - val);

#pragma unroll
    for (int it = 0; it < 4; ++it) {
        int id = it * 256 + t;
        int j = id >> 2, pg = id & 3;
        bf16x8 v = *(const bf16x8*)&xbf[(bc * 256 + j) * 1024 + h * 32 + pg * 8];
        float d = dts[j];
#pragma unroll
        for (int e = 0; e < 8; ++e) tile[j][pg * 8 + e] = (__bf16)((float)v[e] * d);
    }
    __syncthreads();

#pragma unroll
    for (int it = 0; it < 4; ++it) {
        int id = it * 256 + t;
        int p = id >> 5, jg = id & 31;
        bf16x8 o, od;
#pragma unroll
        for (int e = 0; e < 8; ++e) {
            __bf16 v = tile[jg * 8 + e][p];
            o[e] = v;
            od[e] = (__bf16)((float)v * decs[jg * 8 + e]);
        }
        *(bf16x8*)&xdtT[bch * 8192 + p * 256 + jg * 8] = o;
        *(bf16x8*)&xdecT[p * 264 + jg * 8] = od;
    }
    __syncthreads();

    const int fr = lane & 15, quad = lane >> 4, fk = quad * 8;
    const int mt = wave >> 1, ntb = (wave & 1) * 2;
    f32x4 acc[2] = {};
#pragma unroll
    for (int ks = 0; ks < 8; ++ks) {
        bf16x8 af = *(const bf16x8*)&xdecT[(mt * 16 + fr) * 264 + ks * 32 + fk];
#pragma unroll
        for (int nb = 0; nb < 2; ++nb) {
            int n = (ntb + nb) * 16 + fr;
            int ch = (ks * 4 + quad) ^ (n & 7);
            bf16x8 bfv = *(const bf16x8*)&Bsh2[n * 256 + ch * 8];
            acc[nb] = MFMA16(af, bfv, acc[nb]);
        }
    }
    const int rowb = quad * 4;
#pragma unroll
    for (int nb = 0; nb < 2; ++nb)
#pragma unroll
        for (int q = 0; q < 4; ++q) {
            int p = mt * 16 + rowb + q;
            int n = (ntb + nb) * 16 + fr;
            states[bch * 2048 + p * 64 + n] = acc[nb][q];
        }
}

// ---------------------------------------------------------------------------
// scan: prev[b,c] = prev[b,c-1]*exp(alast[c-1]) + states[c-1]; bf16 out.
// ---------------------------------------------------------------------------
__global__ void scan_kernel(const float* __restrict__ states,
                            const float* __restrict__ acum,
                            __bf16* __restrict__ prevbf)
{
    int t = blockIdx.x * 256 + threadIdx.x;
    int n = t & 63, p = (t >> 6) & 31, h = (t >> 11) & 31, b = t >> 16;
    float s = 0.f;
    for (int c = 0; c < 16; ++c) {
        size_t bch = ((size_t)(b * 16 + c) * 32 + h);
        size_t off = bch * 2048 + (size_t)p * 64 + n;
        prevbf[off] = (__bf16)s;
        float dec = __expf(acum[bch * 256 + 255]);
        s = s * dec + states[off];
    }
}

// ---------------------------------------------------------------------------
// y: block=(b,c,h); 4 waves; wave w owns row-subtiles {w, w+4, w+8, w+12}.
// ---------------------------------------------------------------------------
__global__ __launch_bounds__(256, 2) void y_kernel(
    const __bf16* __restrict__ Bbf, const __bf16* __restrict__ Cbf,
    const float* __restrict__ acum, const __bf16* __restrict__ xdtT,
    const __bf16* __restrict__ prevbf, const __bf16* __restrict__ xbf,
    const float* __restrict__ Dp, __bf16* __restrict__ ybf)
{
    const int bidx = blockIdx.x;
    const int bc = bidx & 31, h = bidx >> 5;
    const size_t bch = (size_t)bc * 32 + h;
    __shared__ __attribute__((aligned(16))) __bf16 Bsh[256 * 64];
    __shared__ __attribute__((aligned(16))) __bf16 xsh[32 * 256];
    __shared__ __attribute__((aligned(16))) __bf16 Gw[4][16 * 72];
    __shared__ float ash[256];
    const int t = threadIdx.x, w = t >> 6, lane = t & 63;
    const int fr = lane & 15, q = lane >> 4;

    const __bf16* Bsrc = Bbf + (size_t)bc * 16384;
#pragma unroll
    for (int cc = 0; cc < 8; ++cc) {
        int s = w * 8 + cc;
        int row = s * 8 + (lane >> 3);
        int ch = (lane & 7) ^ ((lane >> 3) & 7);
        async_copy16(Bsrc + row * 64 + ch * 8, Bsh + s * 512);
    }
    const __bf16* xsrc = xdtT + bch * 8192;
#pragma unroll
    for (int cc = 0; cc < 4; ++cc) {
        int s = w * 4 + cc;
        int p = s * 2 + (lane >> 5);
        int cl = lane & 31;
        int ch = (cl & 24) | ((cl & 7) ^ (p & 7));
        async_copy16(xsrc + p * 256 + ch * 8, xsh + s * 512);
    }
    ash[t] = acum[bch * 256 + t];
    __syncthreads();

    bf16x8 cf[4][2], pf[2][2];
    float ei4[4];
#pragma unroll
    for (int s4 = 0; s4 < 4; ++s4) {
        int i = (w + 4 * s4) * 16 + fr;
        const __bf16* cp = Cbf + ((size_t)bc * 256 + i) * 64 + q * 8;
        cf[s4][0] = *(const bf16x8*)cp;
        cf[s4][1] = *(const bf16x8*)(cp + 32);
        ei4[s4] = __expf(ash[i]);
    }
#pragma unroll
    for (int mt = 0; mt < 2; ++mt) {
        const __bf16* pp = prevbf + bch * 2048 + (size_t)(mt * 16 + fr) * 64 + q * 8;
        pf[mt][0] = *(const bf16x8*)pp;
        pf[mt][1] = *(const bf16x8*)(pp + 32);
    }
    float ai[4][4];
#pragma unroll
    for (int s4 = 0; s4 < 4; ++s4)
#pragma unroll
        for (int r = 0; r < 4; ++r)
            ai[s4][r] = ash[(w + 4 * s4) * 16 + q * 4 + r];

    f32x4 acc[4][2] = {};

#pragma unroll
    for (int jt = 0; jt < 4; ++jt) {
        bf16x8 bb[4][2], xa[2][2];
#pragma unroll
        for (int nt = 0; nt < 4; ++nt) {
            int j = jt * 64 + nt * 16 + fr;
#pragma unroll
            for (int ks = 0; ks < 2; ++ks) {
                int ch = (q + 4 * ks) ^ (fr & 7);
                bb[nt][ks] = *(const bf16x8*)&Bsh[j * 64 + ch * 8];
            }
        }
#pragma unroll
        for (int mt = 0; mt < 2; ++mt) {
            int p = mt * 16 + fr;
#pragma unroll
            for (int ks = 0; ks < 2; ++ks) {
                int ch = 8 * jt + ((q + 4 * ks) ^ (p & 7));
                xa[mt][ks] = *(const bf16x8*)&xsh[p * 256 + ch * 8];
            }
        }
#pragma unroll
        for (int s4 = 0; s4 < 4; ++s4) {
            int si = w + 4 * s4;
            if (si < 4 * jt) continue;
            f32x4 sreg[4];
#pragma unroll
            for (int nt = 0; nt < 4; ++nt) {
                f32x4 z = {};
                z = MFMA16(cf[s4][0], bb[nt][0], z);
                z = MFMA16(cf[s4][1], bb[nt][1], z);
                sreg[nt] = z;
            }
#pragma unroll
            for (int nt = 0; nt < 4; ++nt) {
                int j = jt * 64 + nt * 16 + fr;
                float aj = ash[j];
#pragma unroll
                for (int r = 0; r < 4; ++r) {
                    int i = si * 16 + q * 4 + r;
                    float v = (j <= i) ? sreg[nt][r] * __expf(ai[s4][r] - aj) : 0.f;
                    Gw[w][(q * 4 + r) * 72 + nt * 16 + fr] = (__bf16)v;
                }
            }
            bf16x8 g0 = *(const bf16x8*)&Gw[w][fr * 72 + q * 8];
            bf16x8 g1 = *(const bf16x8*)&Gw[w][fr * 72 + 32 + q * 8];
#pragma unroll
            for (int mt = 0; mt < 2; ++mt) {
                acc[s4][mt] = MFMA16(xa[mt][0], g0, acc[s4][mt]);
                acc[s4][mt] = MFMA16(xa[mt][1], g1, acc[s4][mt]);
            }
        }
    }

#pragma unroll
    for (int s4 = 0; s4 < 4; ++s4) {
#pragma unroll
        for (int ks = 0; ks < 2; ++ks) {
            bf16x8 ce;
#pragma unroll
            for (int e = 0; e < 8; ++e)
                ce[e] = (__bf16)((float)cf[s4][ks][e] * ei4[s4]);
#pragma unroll
            for (int mt = 0; mt < 2; ++mt)
                acc[s4][mt] = MFMA16(pf[mt][ks], ce, acc[s4][mt]);
        }
    }

    const float Dv = Dp[h];
#pragma unroll
    for (int s4 = 0; s4 < 4; ++s4) {
        int i = (w + 4 * s4) * 16 + fr;
        size_t row = (size_t)bc * 256 + i;
#pragma unroll
        for (int mt = 0; mt < 2; ++mt) {
            int p0 = mt * 16 + q * 4;
            bf16x4 xv = *(const bf16x4*)&xbf[row * 1024 + h * 32 + p0];
            bf16x4 o;
#pragma unroll
            for (int e = 0; e < 4; ++e)
                o[e] = (__bf16)(acc[s4][mt][e] + (float)xv[e] * Dv);
            *(bf16x4*)&ybf[row * 1024 + h * 32 + p0] = o;
        }
    }
}

// ---------------------------------------------------------------------------
extern "C" void kernel_launch(void* const* d_in, const int* in_sizes, int n_in,
                              void* d_out, int out_size, void* d_ws, size_t ws_size,
                              hipStream_t stream)
{
    (void)in_sizes; (void)n_in; (void)out_size;
    const float* u       = (const float*)d_in[0];
    const float* W_in    = (const float*)d_in[1];
    const float* dt_bias = (const float*)d_in[2];
    const float* A_log   = (const float*)d_in[3];
    const float* Dp      = (const float*)d_in[4];
    const float* W_out   = (const float*)d_in[5];
    float* out = (float*)d_out;

    if (ws_size < 72679424) return;

    char* ws = (char*)d_ws;
    __bf16* u_bf    = (__bf16*)(ws);                  // 16,777,216 (reused as ybf)
    __bf16* win_bf  = (__bf16*)(ws + 16777216);       //  2,424,832
    __bf16* wout_bf = (__bf16*)(ws + 19202048);       //  2,097,152
    __bf16* xbf     = (__bf16*)(ws + 21299200);       // 16,777,216
    float*  dtz     = (float*) (ws + 38076416);       //  1,048,576
    float*  acum    = (float*) (ws + 39124992);       //  1,048,576
    __bf16* xdtT    = (__bf16*)(ws + 40173568);       // 16,777,216
    float*  states  = (float*) (ws + 56950784);       //  8,388,608
    __bf16* prevbf  = (__bf16*)(ws + 65339392);       //  4,194,304
    __bf16* Bbf     = (__bf16*)(ws + 69533696);       //  1,048,576
    __bf16* Cbf     = (__bf16*)(ws + 70582272);       //  1,048,576
    __bf16* BbfT    = (__bf16*)(ws + 71630848);       //  1,048,576

    cvt_all<<<10400, 256, 0, stream>>>(u, u_bf, W_in, win_bf, W_out, wout_bf);

    gemm_fused<<<dim3(128, 10), 256, 0, stream>>>(u_bf, win_bf, 1024, 1184, 1,
                                                  nullptr, xbf, Bbf, Cbf, BbfT, dtz);

    middle_kernel<<<dim3(32, 16, 2), 256, 0, stream>>>(dtz, dt_bias, A_log, xbf,
                                                       BbfT, acum, xdtT, states);
    scan_kernel<<<512, 256, 0, stream>>>(states, acum, prevbf);

    __bf16* ybf = u_bf;  // u_bf dead after gemm1
    y_kernel<<<1024, 256, 0, stream>>>(Bbf, Cbf, acum, xdtT, prevbf,
                                       xbf, Dp, ybf);

    gemm_fused<<<dim3(128, 8), 256, 0, stream>>>(ybf, wout_bf, 1024, 1024, 0,
                                                 out, nullptr, nullptr, nullptr,
                                                 nullptr, nullptr);
}